// Round 1
// baseline (3482.140 us; speedup 1.0000x reference)
//
#include <hip/hip_runtime.h>
#include <math.h>

// Problem constants
constexpr int LINES = 4;                 // lines per block in axis kernels
constexpr float SC0 = 1.0f / 64.0f;      // scale for k=0
constexpr float SC1 = 2.0f / 64.0f;      // scale for k>=1

// strides in floats for layout [b][m][n][z][c], c=32
constexpr int S_B = 64 * 64 * 64 * 32;   // 8388608
constexpr int S_M = 64 * 64 * 32;        // 131072
constexpr int S_N = 64 * 32;             // 2048
constexpr int S_Z = 32;

// ---------------------------------------------------------------------------
// Spectral conv along one axis. Each block processes LINES lines (a line is
// the 32-channel x 64-position slab along the transformed axis).
// Math per line:
//   a[i,k] = sum_m x[i,m] cos(2pi k m/64);  b[i,k] = sum_m x[i,m] sin(2pi k m/64)
//   Ar[o,k] = sum_i wr*a + wi*b;  Ai[o,k] = sum_i wi*a - wr*b
//   y[o,m'] = sum_k s_k (Ar cos(2pi k m'/64) - Ai sin(2pi k m'/64))
// with s_0 = 1/64, s_k = 2/64 (ortho rfft+irfft, modes 0..15, DC imag dropped).
// ---------------------------------------------------------------------------
template <int AXIS, bool ACCUM>
__global__ __launch_bounds__(256)
void spectral_axis_kernel(const float* __restrict__ x,
                          const float* __restrict__ w,
                          float* __restrict__ out)
{
    __shared__ float2 csn[64];                  // (cos, sin)(2*pi*j/64)
    __shared__ float  bufA[LINES * 32 * 68];    // xl [line][i][pos], pad 68; later prs/pis overlay
    __shared__ float  arr[LINES * 32 * 16];     // a[line][i][k]
    __shared__ float  aii[LINES * 32 * 16];     // b[line][i][k]

    const int t = threadIdx.x;

    if (t < 64) {
        float ang = (2.0f * 3.14159265358979323846f / 64.0f) * (float)t;
        float s, c;
        sincosf(ang, &s, &c);
        csn[t] = make_float2(c, s);
    }

    // line bases
    const int l0 = blockIdx.x * LINES;
    long base[LINES];
#pragma unroll
    for (int line = 0; line < LINES; ++line) {
        int l = l0 + line;
        int b = l >> 12, p1 = (l >> 6) & 63, p2 = l & 63;
        long bs;
        if (AXIS == 0)      bs = (long)b * S_B + (long)p1 * S_N + (long)p2 * S_Z;
        else if (AXIS == 1) bs = (long)b * S_B + (long)p1 * S_M + (long)p2 * S_Z;
        else                bs = (long)b * S_B + (long)p1 * S_M + (long)p2 * S_N;
        base[line] = bs;
    }
    constexpr int stride = (AXIS == 0) ? S_M : ((AXIS == 1) ? S_N : S_Z);

    // ---- stage 0: load lines into LDS (transposed to [i][pos]) ----
#pragma unroll
    for (int line = 0; line < LINES; ++line) {
        const float* xb = x + base[line];
#pragma unroll
        for (int v = t, rep = 0; rep < 2; ++rep, v += 256) {
            int pos = v >> 3, i4 = v & 7;
            const float4 val = *reinterpret_cast<const float4*>(xb + (long)pos * stride + i4 * 4);
            float* dst = &bufA[(line * 32 + i4 * 4) * 68 + pos];
            dst[0]      = val.x;
            dst[68]     = val.y;
            dst[2 * 68] = val.z;
            dst[3 * 68] = val.w;
        }
    }
    __syncthreads();

    // ---- stage 1: forward transform a,b = x * [cos|sin]^T ----
    {
        const int i = t >> 3, k0 = t & 7;
#pragma unroll
        for (int line = 0; line < LINES; ++line) {
            const float4* row4 = reinterpret_cast<const float4*>(&bufA[(line * 32 + i) * 68]);
            float a0 = 0.f, b0 = 0.f, a1 = 0.f, b1 = 0.f;
            int j0 = 0, j1 = 0;
            const int k1 = k0 + 8;
            for (int m4 = 0; m4 < 16; ++m4) {
                float4 v = row4[m4];
                {
                    float2 t0 = csn[j0], t1 = csn[j1];
                    a0 += v.x * t0.x; b0 += v.x * t0.y;
                    a1 += v.x * t1.x; b1 += v.x * t1.y;
                    j0 = (j0 + k0) & 63; j1 = (j1 + k1) & 63;
                }
                {
                    float2 t0 = csn[j0], t1 = csn[j1];
                    a0 += v.y * t0.x; b0 += v.y * t0.y;
                    a1 += v.y * t1.x; b1 += v.y * t1.y;
                    j0 = (j0 + k0) & 63; j1 = (j1 + k1) & 63;
                }
                {
                    float2 t0 = csn[j0], t1 = csn[j1];
                    a0 += v.z * t0.x; b0 += v.z * t0.y;
                    a1 += v.z * t1.x; b1 += v.z * t1.y;
                    j0 = (j0 + k0) & 63; j1 = (j1 + k1) & 63;
                }
                {
                    float2 t0 = csn[j0], t1 = csn[j1];
                    a0 += v.w * t0.x; b0 += v.w * t0.y;
                    a1 += v.w * t1.x; b1 += v.w * t1.y;
                    j0 = (j0 + k0) & 63; j1 = (j1 + k1) & 63;
                }
            }
            const int ab = (line * 32 + i) * 16;
            arr[ab + k0]     = a0;
            aii[ab + k0]     = b0;
            arr[ab + k0 + 8] = a1;
            aii[ab + k0 + 8] = b1;
        }
    }
    __syncthreads();

    // ---- stage 2: per-mode complex channel mixing ----
    // prs/pis overlay the (no longer needed) xl region.
    float* prs = bufA;                       // [line][o][17]
    float* pis = bufA + LINES * 32 * 17;     // [line][o][17]
    {
        const int o = t >> 3, k0 = t & 7;
#pragma unroll
        for (int h = 0; h < 2; ++h) {
            const int kk = k0 + 8 * h;
            float Pr[LINES] = {0.f, 0.f, 0.f, 0.f};
            float Pi[LINES] = {0.f, 0.f, 0.f, 0.f};
            for (int ii = 0; ii < 32; ++ii) {
                const float2 wv = *reinterpret_cast<const float2*>(w + ((ii * 32 + o) * 16 + kk) * 2);
#pragma unroll
                for (int line = 0; line < LINES; ++line) {
                    float av = arr[(line * 32 + ii) * 16 + kk];
                    float bv = aii[(line * 32 + ii) * 16 + kk];
                    Pr[line] += wv.x * av + wv.y * bv;
                    Pi[line] += wv.y * av - wv.x * bv;
                }
            }
            const float s = (kk == 0) ? SC0 : SC1;
#pragma unroll
            for (int line = 0; line < LINES; ++line) {
                prs[(line * 32 + o) * 17 + kk] = Pr[line] * s;
                pis[(line * 32 + o) * 17 + kk] = Pi[line] * s;
            }
        }
    }
    __syncthreads();

    // ---- stage 3: inverse transform + global write ----
    {
        const int o = t & 31, mb = t >> 5;   // mb in 0..7
#pragma unroll
        for (int line = 0; line < LINES; ++line) {
            float pr[16], pi[16];
#pragma unroll
            for (int k = 0; k < 16; ++k) {
                pr[k] = prs[(line * 32 + o) * 17 + k];
                pi[k] = pis[(line * 32 + o) * 17 + k];
            }
            float* ob = out + base[line] + o;
#pragma unroll
            for (int ms = 0; ms < 8; ++ms) {
                const int mp = mb * 8 + ms;
                float y = pr[0];             // k=0: cos=1, sin=0
                int jj = mp;
#pragma unroll
                for (int k = 1; k < 16; ++k) {
                    float2 tv = csn[jj];
                    y += pr[k] * tv.x - pi[k] * tv.y;
                    jj = (jj + mp) & 63;
                }
                if (ACCUM) ob[(long)mp * stride] += y;
                else       ob[(long)mp * stride] = y;
            }
        }
    }
}

// ---------------------------------------------------------------------------
// FFN (32 -> 128 ReLU -> 32) + LayerNorm, in place on d_out.
// One point per thread. Weight indices are wave-uniform (scalar-load friendly).
// ---------------------------------------------------------------------------
__global__ __launch_bounds__(256)
void ffn_ln_kernel(float* __restrict__ io,
                   const float* __restrict__ w0, const float* __restrict__ b0,
                   const float* __restrict__ w1, const float* __restrict__ b1,
                   const float* __restrict__ g,  const float* __restrict__ bb)
{
    const int t = threadIdx.x;
    const long p = (long)blockIdx.x * 256 + t;
    float* pp = io + p * 32;

    float s[32];
#pragma unroll
    for (int q = 0; q < 8; ++q) {
        float4 v = *reinterpret_cast<const float4*>(pp + q * 4);
        s[q * 4 + 0] = v.x; s[q * 4 + 1] = v.y; s[q * 4 + 2] = v.z; s[q * 4 + 3] = v.w;
    }

    float y[32];
#pragma unroll
    for (int o = 0; o < 32; ++o) y[o] = b1[o];

    // hidden dim 128 processed in 8 blocks of 16
#pragma unroll
    for (int jb = 0; jb < 8; ++jb) {
        float h[16];
#pragma unroll
        for (int jj = 0; jj < 16; ++jj) h[jj] = b0[jb * 16 + jj];

        for (int i = 0; i < 32; ++i) {
            const float si = s[i];
#pragma unroll
            for (int q = 0; q < 4; ++q) {
                float4 wv = *reinterpret_cast<const float4*>(w0 + i * 128 + jb * 16 + q * 4);
                h[q * 4 + 0] += si * wv.x;
                h[q * 4 + 1] += si * wv.y;
                h[q * 4 + 2] += si * wv.z;
                h[q * 4 + 3] += si * wv.w;
            }
        }

#pragma unroll
        for (int jj = 0; jj < 16; ++jj) {
            const float hv = fmaxf(h[jj], 0.0f);
            const int j = jb * 16 + jj;
#pragma unroll
            for (int q = 0; q < 8; ++q) {
                float4 wv = *reinterpret_cast<const float4*>(w1 + j * 32 + q * 4);
                y[q * 4 + 0] += hv * wv.x;
                y[q * 4 + 1] += hv * wv.y;
                y[q * 4 + 2] += hv * wv.z;
                y[q * 4 + 3] += hv * wv.w;
            }
        }
    }

    // LayerNorm over the 32 outputs
    float mu = 0.f;
#pragma unroll
    for (int o = 0; o < 32; ++o) mu += y[o];
    mu *= (1.0f / 32.0f);
    float var = 0.f;
#pragma unroll
    for (int o = 0; o < 32; ++o) { float d = y[o] - mu; var += d * d; }
    var *= (1.0f / 32.0f);
    const float r = rsqrtf(var + 1e-5f);

#pragma unroll
    for (int q = 0; q < 8; ++q) {
        float4 gv  = *reinterpret_cast<const float4*>(g + q * 4);
        float4 bv  = *reinterpret_cast<const float4*>(bb + q * 4);
        float4 ov;
        ov.x = (y[q * 4 + 0] - mu) * r * gv.x + bv.x;
        ov.y = (y[q * 4 + 1] - mu) * r * gv.y + bv.y;
        ov.z = (y[q * 4 + 2] - mu) * r * gv.z + bv.z;
        ov.w = (y[q * 4 + 3] - mu) * r * gv.w + bv.w;
        *reinterpret_cast<float4*>(pp + q * 4) = ov;
    }
}

extern "C" void kernel_launch(void* const* d_in, const int* in_sizes, int n_in,
                              void* d_out, int out_size, void* d_ws, size_t ws_size,
                              hipStream_t stream)
{
    const float* x    = (const float*)d_in[0];
    const float* wx   = (const float*)d_in[1];
    const float* wy   = (const float*)d_in[2];
    const float* wz   = (const float*)d_in[3];
    const float* w0   = (const float*)d_in[4];
    const float* b0   = (const float*)d_in[5];
    const float* w1   = (const float*)d_in[6];
    const float* b1   = (const float*)d_in[7];
    const float* ln_g = (const float*)d_in[8];
    const float* ln_b = (const float*)d_in[9];
    float* out = (float*)d_out;

    const int nblk = (4 * 64 * 64) / LINES;   // 4096

    spectral_axis_kernel<0, false><<<nblk, 256, 0, stream>>>(x, wx, out);
    spectral_axis_kernel<1, true ><<<nblk, 256, 0, stream>>>(x, wy, out);
    spectral_axis_kernel<2, true ><<<nblk, 256, 0, stream>>>(x, wz, out);

    const int npts = 4 * 64 * 64 * 64;        // 1048576
    ffn_ln_kernel<<<npts / 256, 256, 0, stream>>>(out, w0, b0, w1, b1, ln_g, ln_b);
}

// Round 2
// 884.818 us; speedup vs baseline: 3.9354x; 3.9354x over previous
//
#include <hip/hip_runtime.h>
#include <math.h>

constexpr int LINES = 4;
constexpr float SC0 = 1.0f / 64.0f;
constexpr float SC1 = 2.0f / 64.0f;
constexpr float THETA = 6.28318530717958647692f / 64.0f;  // 2*pi/64

// strides in floats for layout [b][m][n][z][c], c=32
constexpr int S_B = 64 * 64 * 64 * 32;
constexpr int S_M = 64 * 64 * 32;
constexpr int S_N = 64 * 32;
constexpr int S_Z = 32;

// ---------------------------------------------------------------------------
// Spectral conv along one axis. Block = 256 threads, LINES=4 lines.
//   a[i,k] = sum_m x[i,m] cos(k m th);  b[i,k] = sum_m x[i,m] sin(k m th)
//   Pr[o,k] = s_k(sum_i wr*a + wi*b);  Pi[o,k] = s_k(sum_i wi*a - wr*b)
//   y[o,m'] = Pr[o,0] + sum_{k>=1} Pr cos(k m' th) - Pi sin(k m' th)
// Trig via in-register rotation (no LDS table). All LDS traffic b128 where
// possible with conflict-checked strides.
// ---------------------------------------------------------------------------
template <int AXIS, bool ACCUM>
__global__ __launch_bounds__(256)
void spectral_axis_kernel(const float* __restrict__ x,
                          const float* __restrict__ w,
                          float* __restrict__ out)
{
    __shared__ float xl [LINES * 32 * 68];   // [line][i][pos], stride 68
    __shared__ float arr[LINES * 16 * 36];   // [line][k][i],  stride 36
    __shared__ float aii[LINES * 16 * 36];

    // P overlays xl after stage 1 (barrier-protected)
    float* prs = xl;                          // [line][o][k], stride 20
    float* pis = xl + LINES * 32 * 20;

    const int t = threadIdx.x;
    const int l0 = blockIdx.x * LINES;
    long base[LINES];
#pragma unroll
    for (int line = 0; line < LINES; ++line) {
        int l = l0 + line;
        int b = l >> 12, p1 = (l >> 6) & 63, p2 = l & 63;
        long bs;
        if (AXIS == 0)      bs = (long)b * S_B + (long)p1 * S_N + (long)p2 * S_Z;
        else if (AXIS == 1) bs = (long)b * S_B + (long)p1 * S_M + (long)p2 * S_Z;
        else                bs = (long)b * S_B + (long)p1 * S_M + (long)p2 * S_N;
        base[line] = bs;
    }
    constexpr int stride = (AXIS == 0) ? S_M : ((AXIS == 1) ? S_N : S_Z);

    // ---- stage 0: global -> LDS, transposed to [i][pos] ----
#pragma unroll
    for (int line = 0; line < LINES; ++line) {
        const float* xb = x + base[line];
#pragma unroll
        for (int v = t, rep = 0; rep < 2; ++rep, v += 256) {
            int pos = v >> 3, i4 = v & 7;
            const float4 val = *reinterpret_cast<const float4*>(xb + (long)pos * stride + i4 * 4);
            float* dst = &xl[(line * 32 + i4 * 4) * 68 + pos];
            dst[0]      = val.x;
            dst[68]     = val.y;
            dst[2 * 68] = val.z;
            dst[3 * 68] = val.w;
        }
    }
    __syncthreads();

    // ---- stage 1: forward transform via register rotation ----
    {
        const int i = t >> 3, k0 = t & 7;
        float sk0, ck0, sk1, ck1;
        sincosf(THETA * (float)k0,       &sk0, &ck0);
        sincosf(THETA * (float)(k0 + 8), &sk1, &ck1);

        float a0[LINES], b0a[LINES], a1[LINES], b1a[LINES];
#pragma unroll
        for (int l = 0; l < LINES; ++l) { a0[l] = 0.f; b0a[l] = 0.f; a1[l] = 0.f; b1a[l] = 0.f; }

        float c0 = 1.f, s0 = 0.f, c1 = 1.f, s1 = 0.f;
        const float4* row[LINES];
#pragma unroll
        for (int l = 0; l < LINES; ++l)
            row[l] = reinterpret_cast<const float4*>(&xl[(l * 32 + i) * 68]);

        for (int m4 = 0; m4 < 16; ++m4) {
            float4 v[LINES];
#pragma unroll
            for (int l = 0; l < LINES; ++l) v[l] = row[l][m4];
#pragma unroll
            for (int e = 0; e < 4; ++e) {
#pragma unroll
                for (int l = 0; l < LINES; ++l) {
                    const float ve = (e == 0) ? v[l].x : (e == 1) ? v[l].y : (e == 2) ? v[l].z : v[l].w;
                    a0[l]  = fmaf(ve, c0, a0[l]);
                    b0a[l] = fmaf(ve, s0, b0a[l]);
                    a1[l]  = fmaf(ve, c1, a1[l]);
                    b1a[l] = fmaf(ve, s1, b1a[l]);
                }
                float nc0 = c0 * ck0 - s0 * sk0, ns0 = s0 * ck0 + c0 * sk0;
                c0 = nc0; s0 = ns0;
                float nc1 = c1 * ck1 - s1 * sk1, ns1 = s1 * ck1 + c1 * sk1;
                c1 = nc1; s1 = ns1;
            }
        }
#pragma unroll
        for (int l = 0; l < LINES; ++l) {
            arr[(l * 16 + k0    ) * 36 + i] = a0[l];
            arr[(l * 16 + k0 + 8) * 36 + i] = a1[l];
            aii[(l * 16 + k0    ) * 36 + i] = b0a[l];
            aii[(l * 16 + k0 + 8) * 36 + i] = b1a[l];
        }
    }
    __syncthreads();

    // ---- stage 2: per-mode complex channel mixing ----
    {
        const int o = t >> 3, k0 = t & 7;
#pragma unroll
        for (int h = 0; h < 2; ++h) {
            const int kk = k0 + 8 * h;
            float Pr[LINES] = {0.f, 0.f, 0.f, 0.f};
            float Pi[LINES] = {0.f, 0.f, 0.f, 0.f};
            for (int q = 0; q < 8; ++q) {
                float4 av[LINES], bv[LINES];
#pragma unroll
                for (int l = 0; l < LINES; ++l) {
                    av[l] = *reinterpret_cast<const float4*>(&arr[(l * 16 + kk) * 36 + 4 * q]);
                    bv[l] = *reinterpret_cast<const float4*>(&aii[(l * 16 + kk) * 36 + 4 * q]);
                }
                float2 wv0 = *reinterpret_cast<const float2*>(w + (((4 * q + 0) * 32 + o) * 16 + kk) * 2);
                float2 wv1 = *reinterpret_cast<const float2*>(w + (((4 * q + 1) * 32 + o) * 16 + kk) * 2);
                float2 wv2 = *reinterpret_cast<const float2*>(w + (((4 * q + 2) * 32 + o) * 16 + kk) * 2);
                float2 wv3 = *reinterpret_cast<const float2*>(w + (((4 * q + 3) * 32 + o) * 16 + kk) * 2);
#pragma unroll
                for (int l = 0; l < LINES; ++l) {
                    Pr[l] = fmaf(wv0.x, av[l].x, Pr[l]); Pr[l] = fmaf(wv0.y, bv[l].x, Pr[l]);
                    Pi[l] = fmaf(wv0.y, av[l].x, Pi[l]); Pi[l] = fmaf(-wv0.x, bv[l].x, Pi[l]);
                    Pr[l] = fmaf(wv1.x, av[l].y, Pr[l]); Pr[l] = fmaf(wv1.y, bv[l].y, Pr[l]);
                    Pi[l] = fmaf(wv1.y, av[l].y, Pi[l]); Pi[l] = fmaf(-wv1.x, bv[l].y, Pi[l]);
                    Pr[l] = fmaf(wv2.x, av[l].z, Pr[l]); Pr[l] = fmaf(wv2.y, bv[l].z, Pr[l]);
                    Pi[l] = fmaf(wv2.y, av[l].z, Pi[l]); Pi[l] = fmaf(-wv2.x, bv[l].z, Pi[l]);
                    Pr[l] = fmaf(wv3.x, av[l].w, Pr[l]); Pr[l] = fmaf(wv3.y, bv[l].w, Pr[l]);
                    Pi[l] = fmaf(wv3.y, av[l].w, Pi[l]); Pi[l] = fmaf(-wv3.x, bv[l].w, Pi[l]);
                }
            }
            const float sc = (kk == 0) ? SC0 : SC1;
#pragma unroll
            for (int l = 0; l < LINES; ++l) {
                prs[(l * 32 + o) * 20 + kk] = Pr[l] * sc;
                pis[(l * 32 + o) * 20 + kk] = Pi[l] * sc;
            }
        }
    }
    __syncthreads();

    // ---- stage 3: inverse transform via register rotation + global write ----
    {
        const int o = t & 31, mb = t >> 5;
#pragma unroll
        for (int pass = 0; pass < 2; ++pass) {
            float pr[2][16], pi[2][16];
#pragma unroll
            for (int l2 = 0; l2 < 2; ++l2) {
                const int line = pass * 2 + l2;
#pragma unroll
                for (int q = 0; q < 4; ++q) {
                    float4 v1 = *reinterpret_cast<const float4*>(&prs[(line * 32 + o) * 20 + 4 * q]);
                    pr[l2][4 * q + 0] = v1.x; pr[l2][4 * q + 1] = v1.y;
                    pr[l2][4 * q + 2] = v1.z; pr[l2][4 * q + 3] = v1.w;
                    float4 v2 = *reinterpret_cast<const float4*>(&pis[(line * 32 + o) * 20 + 4 * q]);
                    pi[l2][4 * q + 0] = v2.x; pi[l2][4 * q + 1] = v2.y;
                    pi[l2][4 * q + 2] = v2.z; pi[l2][4 * q + 3] = v2.w;
                }
            }
#pragma unroll
            for (int ms = 0; ms < 8; ++ms) {
                const int mp = mb * 8 + ms;
                float sst, cst;
                sincosf(THETA * (float)mp, &sst, &cst);
                float c = cst, s = sst;
                float y0 = pr[0][0], y1 = pr[1][0];
#pragma unroll
                for (int k = 1; k < 16; ++k) {
                    y0 = fmaf(pr[0][k], c, y0); y0 = fmaf(-pi[0][k], s, y0);
                    y1 = fmaf(pr[1][k], c, y1); y1 = fmaf(-pi[1][k], s, y1);
                    float nc = c * cst - s * sst, ns = s * cst + c * sst;
                    c = nc; s = ns;
                }
                float* p0 = out + base[pass * 2 + 0] + (long)mp * stride + o;
                float* p1 = out + base[pass * 2 + 1] + (long)mp * stride + o;
                if (ACCUM) { *p0 += y0; *p1 += y1; }
                else       { *p0 = y0;  *p1 = y1; }
            }
        }
    }
}

// ---------------------------------------------------------------------------
// FFN (32 -> 128 ReLU -> 32) + LayerNorm, in place. Weights staged in LDS
// (broadcast reads). 2 points per thread (512 points / block).
// ---------------------------------------------------------------------------
__global__ __launch_bounds__(256)
void ffn_ln_kernel(float* __restrict__ io,
                   const float* __restrict__ w0, const float* __restrict__ b0,
                   const float* __restrict__ w1, const float* __restrict__ b1,
                   const float* __restrict__ g,  const float* __restrict__ bb)
{
    __shared__ float w0s[4096];   // [i=32][j=128]
    __shared__ float w1s[4096];   // [j=128][o=32]
    __shared__ float b0s[128], b1s[32], gs[32], bbs[32];

    const int t = threadIdx.x;
#pragma unroll
    for (int r = 0; r < 4; ++r) {
        reinterpret_cast<float4*>(w0s)[t + 256 * r] = reinterpret_cast<const float4*>(w0)[t + 256 * r];
        reinterpret_cast<float4*>(w1s)[t + 256 * r] = reinterpret_cast<const float4*>(w1)[t + 256 * r];
    }
    if (t < 128) b0s[t] = b0[t];
    if (t < 32) { b1s[t] = b1[t]; gs[t] = g[t]; bbs[t] = bb[t]; }
    __syncthreads();

    const long pbase = (long)blockIdx.x * 512;
    float* pp0 = io + (pbase + t) * 32;
    float* pp1 = io + (pbase + 256 + t) * 32;

    float s0[32], s1[32];
#pragma unroll
    for (int q = 0; q < 8; ++q) {
        float4 v0 = *reinterpret_cast<const float4*>(pp0 + 4 * q);
        s0[4 * q + 0] = v0.x; s0[4 * q + 1] = v0.y; s0[4 * q + 2] = v0.z; s0[4 * q + 3] = v0.w;
        float4 v1 = *reinterpret_cast<const float4*>(pp1 + 4 * q);
        s1[4 * q + 0] = v1.x; s1[4 * q + 1] = v1.y; s1[4 * q + 2] = v1.z; s1[4 * q + 3] = v1.w;
    }

    float y0[32], y1[32];
#pragma unroll
    for (int o = 0; o < 32; ++o) { y0[o] = b1s[o]; y1[o] = y0[o]; }

    // hidden dim 128 in 8 chunks of 16
#pragma unroll
    for (int jb = 0; jb < 8; ++jb) {
        float h0[16], h1[16];
#pragma unroll
        for (int jj = 0; jj < 16; ++jj) { h0[jj] = b0s[jb * 16 + jj]; h1[jj] = h0[jj]; }

        for (int i = 0; i < 32; ++i) {
            const float a0 = s0[i], a1 = s1[i];
#pragma unroll
            for (int q = 0; q < 4; ++q) {
                float4 wv = *reinterpret_cast<const float4*>(&w0s[i * 128 + jb * 16 + 4 * q]);
                h0[4 * q + 0] = fmaf(a0, wv.x, h0[4 * q + 0]);
                h0[4 * q + 1] = fmaf(a0, wv.y, h0[4 * q + 1]);
                h0[4 * q + 2] = fmaf(a0, wv.z, h0[4 * q + 2]);
                h0[4 * q + 3] = fmaf(a0, wv.w, h0[4 * q + 3]);
                h1[4 * q + 0] = fmaf(a1, wv.x, h1[4 * q + 0]);
                h1[4 * q + 1] = fmaf(a1, wv.y, h1[4 * q + 1]);
                h1[4 * q + 2] = fmaf(a1, wv.z, h1[4 * q + 2]);
                h1[4 * q + 3] = fmaf(a1, wv.w, h1[4 * q + 3]);
            }
        }

#pragma unroll
        for (int jj = 0; jj < 16; ++jj) {
            const float hv0 = fmaxf(h0[jj], 0.f);
            const float hv1 = fmaxf(h1[jj], 0.f);
            const int j = jb * 16 + jj;
#pragma unroll
            for (int q = 0; q < 8; ++q) {
                float4 wv = *reinterpret_cast<const float4*>(&w1s[j * 32 + 4 * q]);
                y0[4 * q + 0] = fmaf(hv0, wv.x, y0[4 * q + 0]);
                y0[4 * q + 1] = fmaf(hv0, wv.y, y0[4 * q + 1]);
                y0[4 * q + 2] = fmaf(hv0, wv.z, y0[4 * q + 2]);
                y0[4 * q + 3] = fmaf(hv0, wv.w, y0[4 * q + 3]);
                y1[4 * q + 0] = fmaf(hv1, wv.x, y1[4 * q + 0]);
                y1[4 * q + 1] = fmaf(hv1, wv.y, y1[4 * q + 1]);
                y1[4 * q + 2] = fmaf(hv1, wv.z, y1[4 * q + 2]);
                y1[4 * q + 3] = fmaf(hv1, wv.w, y1[4 * q + 3]);
            }
        }
    }

    // LayerNorm per point
    float mu0 = 0.f, mu1 = 0.f;
#pragma unroll
    for (int o = 0; o < 32; ++o) { mu0 += y0[o]; mu1 += y1[o]; }
    mu0 *= (1.0f / 32.0f); mu1 *= (1.0f / 32.0f);
    float va0 = 0.f, va1 = 0.f;
#pragma unroll
    for (int o = 0; o < 32; ++o) {
        float d0 = y0[o] - mu0; va0 = fmaf(d0, d0, va0);
        float d1 = y1[o] - mu1; va1 = fmaf(d1, d1, va1);
    }
    const float r0 = rsqrtf(va0 * (1.0f / 32.0f) + 1e-5f);
    const float r1 = rsqrtf(va1 * (1.0f / 32.0f) + 1e-5f);

#pragma unroll
    for (int q = 0; q < 8; ++q) {
        float4 ov0, ov1;
        ov0.x = (y0[4 * q + 0] - mu0) * r0 * gs[4 * q + 0] + bbs[4 * q + 0];
        ov0.y = (y0[4 * q + 1] - mu0) * r0 * gs[4 * q + 1] + bbs[4 * q + 1];
        ov0.z = (y0[4 * q + 2] - mu0) * r0 * gs[4 * q + 2] + bbs[4 * q + 2];
        ov0.w = (y0[4 * q + 3] - mu0) * r0 * gs[4 * q + 3] + bbs[4 * q + 3];
        *reinterpret_cast<float4*>(pp0 + 4 * q) = ov0;
        ov1.x = (y1[4 * q + 0] - mu1) * r1 * gs[4 * q + 0] + bbs[4 * q + 0];
        ov1.y = (y1[4 * q + 1] - mu1) * r1 * gs[4 * q + 1] + bbs[4 * q + 1];
        ov1.z = (y1[4 * q + 2] - mu1) * r1 * gs[4 * q + 2] + bbs[4 * q + 2];
        ov1.w = (y1[4 * q + 3] - mu1) * r1 * gs[4 * q + 3] + bbs[4 * q + 3];
        *reinterpret_cast<float4*>(pp1 + 4 * q) = ov1;
    }
}

extern "C" void kernel_launch(void* const* d_in, const int* in_sizes, int n_in,
                              void* d_out, int out_size, void* d_ws, size_t ws_size,
                              hipStream_t stream)
{
    const float* x    = (const float*)d_in[0];
    const float* wx   = (const float*)d_in[1];
    const float* wy   = (const float*)d_in[2];
    const float* wz   = (const float*)d_in[3];
    const float* w0   = (const float*)d_in[4];
    const float* b0   = (const float*)d_in[5];
    const float* w1   = (const float*)d_in[6];
    const float* b1   = (const float*)d_in[7];
    const float* ln_g = (const float*)d_in[8];
    const float* ln_b = (const float*)d_in[9];
    float* out = (float*)d_out;

    const int nblk = (4 * 64 * 64) / LINES;   // 4096

    spectral_axis_kernel<0, false><<<nblk, 256, 0, stream>>>(x, wx, out);
    spectral_axis_kernel<1, true ><<<nblk, 256, 0, stream>>>(x, wy, out);
    spectral_axis_kernel<2, true ><<<nblk, 256, 0, stream>>>(x, wz, out);

    const int npts = 4 * 64 * 64 * 64;        // 1048576
    ffn_ln_kernel<<<npts / 256 / 2, 256, 0, stream>>>(out, w0, b0, w1, b1, ln_g, ln_b);
}

// Round 3
// 487.558 us; speedup vs baseline: 7.1420x; 1.8148x over previous
//
#include <hip/hip_runtime.h>
#include <math.h>

constexpr int LINES = 4;
constexpr float SC0 = 1.0f / 64.0f;
constexpr float SC1 = 2.0f / 64.0f;
constexpr float THETA = 6.28318530717958647692f / 64.0f;  // 2*pi/64

// strides in floats for layout [b][m][n][z][c], c=32
constexpr int S_B = 64 * 64 * 64 * 32;
constexpr int S_M = 64 * 64 * 32;
constexpr int S_N = 64 * 32;
constexpr int S_Z = 32;

// ---------------------------------------------------------------------------
// Spectral conv along one axis (unchanged from round 2; ~121 us each).
// ---------------------------------------------------------------------------
template <int AXIS, bool ACCUM>
__global__ __launch_bounds__(256)
void spectral_axis_kernel(const float* __restrict__ x,
                          const float* __restrict__ w,
                          float* __restrict__ out)
{
    __shared__ float xl [LINES * 32 * 68];   // [line][i][pos], stride 68
    __shared__ float arr[LINES * 16 * 36];   // [line][k][i],  stride 36
    __shared__ float aii[LINES * 16 * 36];

    float* prs = xl;                          // [line][o][k], stride 20 (overlay)
    float* pis = xl + LINES * 32 * 20;

    const int t = threadIdx.x;
    const int l0 = blockIdx.x * LINES;
    long base[LINES];
#pragma unroll
    for (int line = 0; line < LINES; ++line) {
        int l = l0 + line;
        int b = l >> 12, p1 = (l >> 6) & 63, p2 = l & 63;
        long bs;
        if (AXIS == 0)      bs = (long)b * S_B + (long)p1 * S_N + (long)p2 * S_Z;
        else if (AXIS == 1) bs = (long)b * S_B + (long)p1 * S_M + (long)p2 * S_Z;
        else                bs = (long)b * S_B + (long)p1 * S_M + (long)p2 * S_N;
        base[line] = bs;
    }
    constexpr int stride = (AXIS == 0) ? S_M : ((AXIS == 1) ? S_N : S_Z);

#pragma unroll
    for (int line = 0; line < LINES; ++line) {
        const float* xb = x + base[line];
#pragma unroll
        for (int v = t, rep = 0; rep < 2; ++rep, v += 256) {
            int pos = v >> 3, i4 = v & 7;
            const float4 val = *reinterpret_cast<const float4*>(xb + (long)pos * stride + i4 * 4);
            float* dst = &xl[(line * 32 + i4 * 4) * 68 + pos];
            dst[0]      = val.x;
            dst[68]     = val.y;
            dst[2 * 68] = val.z;
            dst[3 * 68] = val.w;
        }
    }
    __syncthreads();

    {
        const int i = t >> 3, k0 = t & 7;
        float sk0, ck0, sk1, ck1;
        sincosf(THETA * (float)k0,       &sk0, &ck0);
        sincosf(THETA * (float)(k0 + 8), &sk1, &ck1);

        float a0[LINES], b0a[LINES], a1[LINES], b1a[LINES];
#pragma unroll
        for (int l = 0; l < LINES; ++l) { a0[l] = 0.f; b0a[l] = 0.f; a1[l] = 0.f; b1a[l] = 0.f; }

        float c0 = 1.f, s0 = 0.f, c1 = 1.f, s1 = 0.f;
        const float4* row[LINES];
#pragma unroll
        for (int l = 0; l < LINES; ++l)
            row[l] = reinterpret_cast<const float4*>(&xl[(l * 32 + i) * 68]);

        for (int m4 = 0; m4 < 16; ++m4) {
            float4 v[LINES];
#pragma unroll
            for (int l = 0; l < LINES; ++l) v[l] = row[l][m4];
#pragma unroll
            for (int e = 0; e < 4; ++e) {
#pragma unroll
                for (int l = 0; l < LINES; ++l) {
                    const float ve = (e == 0) ? v[l].x : (e == 1) ? v[l].y : (e == 2) ? v[l].z : v[l].w;
                    a0[l]  = fmaf(ve, c0, a0[l]);
                    b0a[l] = fmaf(ve, s0, b0a[l]);
                    a1[l]  = fmaf(ve, c1, a1[l]);
                    b1a[l] = fmaf(ve, s1, b1a[l]);
                }
                float nc0 = c0 * ck0 - s0 * sk0, ns0 = s0 * ck0 + c0 * sk0;
                c0 = nc0; s0 = ns0;
                float nc1 = c1 * ck1 - s1 * sk1, ns1 = s1 * ck1 + c1 * sk1;
                c1 = nc1; s1 = ns1;
            }
        }
#pragma unroll
        for (int l = 0; l < LINES; ++l) {
            arr[(l * 16 + k0    ) * 36 + i] = a0[l];
            arr[(l * 16 + k0 + 8) * 36 + i] = a1[l];
            aii[(l * 16 + k0    ) * 36 + i] = b0a[l];
            aii[(l * 16 + k0 + 8) * 36 + i] = b1a[l];
        }
    }
    __syncthreads();

    {
        const int o = t >> 3, k0 = t & 7;
#pragma unroll
        for (int h = 0; h < 2; ++h) {
            const int kk = k0 + 8 * h;
            float Pr[LINES] = {0.f, 0.f, 0.f, 0.f};
            float Pi[LINES] = {0.f, 0.f, 0.f, 0.f};
            for (int q = 0; q < 8; ++q) {
                float4 av[LINES], bv[LINES];
#pragma unroll
                for (int l = 0; l < LINES; ++l) {
                    av[l] = *reinterpret_cast<const float4*>(&arr[(l * 16 + kk) * 36 + 4 * q]);
                    bv[l] = *reinterpret_cast<const float4*>(&aii[(l * 16 + kk) * 36 + 4 * q]);
                }
                float2 wv0 = *reinterpret_cast<const float2*>(w + (((4 * q + 0) * 32 + o) * 16 + kk) * 2);
                float2 wv1 = *reinterpret_cast<const float2*>(w + (((4 * q + 1) * 32 + o) * 16 + kk) * 2);
                float2 wv2 = *reinterpret_cast<const float2*>(w + (((4 * q + 2) * 32 + o) * 16 + kk) * 2);
                float2 wv3 = *reinterpret_cast<const float2*>(w + (((4 * q + 3) * 32 + o) * 16 + kk) * 2);
#pragma unroll
                for (int l = 0; l < LINES; ++l) {
                    Pr[l] = fmaf(wv0.x, av[l].x, Pr[l]); Pr[l] = fmaf(wv0.y, bv[l].x, Pr[l]);
                    Pi[l] = fmaf(wv0.y, av[l].x, Pi[l]); Pi[l] = fmaf(-wv0.x, bv[l].x, Pi[l]);
                    Pr[l] = fmaf(wv1.x, av[l].y, Pr[l]); Pr[l] = fmaf(wv1.y, bv[l].y, Pr[l]);
                    Pi[l] = fmaf(wv1.y, av[l].y, Pi[l]); Pi[l] = fmaf(-wv1.x, bv[l].y, Pi[l]);
                    Pr[l] = fmaf(wv2.x, av[l].z, Pr[l]); Pr[l] = fmaf(wv2.y, bv[l].z, Pr[l]);
                    Pi[l] = fmaf(wv2.y, av[l].z, Pi[l]); Pi[l] = fmaf(-wv2.x, bv[l].z, Pi[l]);
                    Pr[l] = fmaf(wv3.x, av[l].w, Pr[l]); Pr[l] = fmaf(wv3.y, bv[l].w, Pr[l]);
                    Pi[l] = fmaf(wv3.y, av[l].w, Pi[l]); Pi[l] = fmaf(-wv3.x, bv[l].w, Pi[l]);
                }
            }
            const float sc = (kk == 0) ? SC0 : SC1;
#pragma unroll
            for (int l = 0; l < LINES; ++l) {
                prs[(l * 32 + o) * 20 + kk] = Pr[l] * sc;
                pis[(l * 32 + o) * 20 + kk] = Pi[l] * sc;
            }
        }
    }
    __syncthreads();

    {
        const int o = t & 31, mb = t >> 5;
#pragma unroll
        for (int pass = 0; pass < 2; ++pass) {
            float pr[2][16], pi[2][16];
#pragma unroll
            for (int l2 = 0; l2 < 2; ++l2) {
                const int line = pass * 2 + l2;
#pragma unroll
                for (int q = 0; q < 4; ++q) {
                    float4 v1 = *reinterpret_cast<const float4*>(&prs[(line * 32 + o) * 20 + 4 * q]);
                    pr[l2][4 * q + 0] = v1.x; pr[l2][4 * q + 1] = v1.y;
                    pr[l2][4 * q + 2] = v1.z; pr[l2][4 * q + 3] = v1.w;
                    float4 v2 = *reinterpret_cast<const float4*>(&pis[(line * 32 + o) * 20 + 4 * q]);
                    pi[l2][4 * q + 0] = v2.x; pi[l2][4 * q + 1] = v2.y;
                    pi[l2][4 * q + 2] = v2.z; pi[l2][4 * q + 3] = v2.w;
                }
            }
#pragma unroll
            for (int ms = 0; ms < 8; ++ms) {
                const int mp = mb * 8 + ms;
                float sst, cst;
                sincosf(THETA * (float)mp, &sst, &cst);
                float c = cst, s = sst;
                float y0 = pr[0][0], y1 = pr[1][0];
#pragma unroll
                for (int k = 1; k < 16; ++k) {
                    y0 = fmaf(pr[0][k], c, y0); y0 = fmaf(-pi[0][k], s, y0);
                    y1 = fmaf(pr[1][k], c, y1); y1 = fmaf(-pi[1][k], s, y1);
                    float nc = c * cst - s * sst, ns = s * cst + c * sst;
                    c = nc; s = ns;
                }
                float* p0 = out + base[pass * 2 + 0] + (long)mp * stride + o;
                float* p1 = out + base[pass * 2 + 1] + (long)mp * stride + o;
                if (ACCUM) { *p0 += y0; *p1 += y1; }
                else       { *p0 = y0;  *p1 = y1; }
            }
        }
    }
}

// ---------------------------------------------------------------------------
// FFN (32 -> 128 ReLU -> 32) + LayerNorm via bf16 MFMA, in place.
// Block = 4 waves; each wave owns 64-point tiles (4 tiles/wave).
// GEMM1: H = S @ W0 (+b0), ReLU -> bf16 via per-wave LDS transpose ->
// GEMM2: Y = H @ W1 (+b1) -> LN via 16-lane shfl_xor reduce -> store.
// Fragment conventions (mfma_f32_16x16x32_bf16):
//   A: row = l&15, k-slot = (l>>4, e)  |  B: col = l&15, same k-slot map
//   (A and B use the SAME k bijection k=8*(l>>4)+e -> result independent of
//    the HW's internal k ordering)
//   D: col = l&15, row = (l>>4)*4 + reg   [verified layout]
// ---------------------------------------------------------------------------
typedef __attribute__((ext_vector_type(8))) short short8v;
typedef __attribute__((ext_vector_type(4))) float float4v;

__device__ __forceinline__ unsigned short f2bf(float f) {
    unsigned int u = __builtin_bit_cast(unsigned int, f);
    u += 0x7FFFu + ((u >> 16) & 1u);
    return (unsigned short)(u >> 16);
}

__global__ __launch_bounds__(256)
void ffn_ln_mfma_kernel(float* __restrict__ io,
                        const float* __restrict__ w0, const float* __restrict__ b0,
                        const float* __restrict__ w1, const float* __restrict__ b1,
                        const float* __restrict__ g,  const float* __restrict__ bb)
{
    // smem halves: [0,4096) w0 frags, [4096,8192) w1 frags,
    // [8192, 8192+4*5120) per-wave H buffers (128 rows x 40 halves, dbuf by 64 rows)
    __shared__ unsigned short smem[28672];

    const int t = threadIdx.x;
    const int lane = t & 63, wave = t >> 6;
    const int gq = lane >> 4, c = lane & 15;

    // ---- stage weight fragments into LDS (block-cooperative, once) ----
    for (int s = t; s < 512; s += 256) {
        const int n = s >> 6, ln = s & 63, g2 = ln >> 4, c2 = ln & 15;
        const int kb = n >> 1, nn = n & 1;
        short8v v0, v1;
#pragma unroll
        for (int e = 0; e < 8; ++e) {
            v0[e] = (short)f2bf(w0[(8 * g2 + e) * 128 + n * 16 + c2]);
            v1[e] = (short)f2bf(w1[(32 * kb + 8 * g2 + e) * 32 + nn * 16 + c2]);
        }
        *reinterpret_cast<short8v*>(&smem[s * 8])        = v0;
        *reinterpret_cast<short8v*>(&smem[4096 + s * 8]) = v1;
    }
    __syncthreads();

    // hoisted per-lane constants (col = 16n + c)
    float b0v[8], b1v[2], gv[2], bv[2];
#pragma unroll
    for (int n = 0; n < 8; ++n) b0v[n] = b0[n * 16 + c];
#pragma unroll
    for (int n = 0; n < 2; ++n) { b1v[n] = b1[n * 16 + c]; gv[n] = g[n * 16 + c]; bv[n] = bb[n * 16 + c]; }

    const int Hbase = 8192 + wave * 5120;

    for (int ti = 0; ti < 4; ++ti) {
        const int tile = (blockIdx.x * 4 + wave) * 4 + ti;
        const long p0 = (long)tile * 64;
        float* pio = io + p0 * 32;

        // ---- load S fragments (A for GEMM1): row = 16f + c, k = 8*gq + e ----
        short8v af[4];
#pragma unroll
        for (int f = 0; f < 4; ++f) {
            const float* sp = pio + (16 * f + c) * 32 + 8 * gq;
            float4 lo = *reinterpret_cast<const float4*>(sp);
            float4 hi = *reinterpret_cast<const float4*>(sp + 4);
            af[f][0] = (short)f2bf(lo.x); af[f][1] = (short)f2bf(lo.y);
            af[f][2] = (short)f2bf(lo.z); af[f][3] = (short)f2bf(lo.w);
            af[f][4] = (short)f2bf(hi.x); af[f][5] = (short)f2bf(hi.y);
            af[f][6] = (short)f2bf(hi.z); af[f][7] = (short)f2bf(hi.w);
        }

        float4v Y[4][2];
#pragma unroll
        for (int f = 0; f < 4; ++f)
#pragma unroll
            for (int n = 0; n < 2; ++n)
                Y[f][n] = float4v{b1v[n], b1v[n], b1v[n], b1v[n]};

        // ---- K loop over hidden dim in 4 chunks of 32 ----
#pragma unroll
        for (int kb = 0; kb < 4; ++kb) {
            const int rb = (kb & 1) * 64;   // H double buffer row base

            // GEMM1 partial (hidden cols 32kb..32kb+31) + ReLU + bf16 -> LDS
#pragma unroll
            for (int nn = 0; nn < 2; ++nn) {
                const int n = 2 * kb + nn;
                const short8v wv = *reinterpret_cast<const short8v*>(&smem[(n * 64 + lane) * 8]);
#pragma unroll
                for (int f = 0; f < 4; ++f) {
                    float4v hacc = float4v{b0v[n], b0v[n], b0v[n], b0v[n]};
                    hacc = __builtin_amdgcn_mfma_f32_16x16x32_bf16(af[f], wv, hacc, 0, 0, 0);
#pragma unroll
                    for (int r = 0; r < 4; ++r) {
                        const float hv = fmaxf(hacc[r], 0.0f);
                        smem[Hbase + (rb + 16 * f + 4 * gq + r) * 40 + nn * 16 + c] = f2bf(hv);
                    }
                }
            }

            // GEMM2 K-step: A2 from LDS (row = 16f + c, k = 8*gq + e)
            const short8v wva = *reinterpret_cast<const short8v*>(&smem[4096 + ((kb * 2 + 0) * 64 + lane) * 8]);
            const short8v wvb = *reinterpret_cast<const short8v*>(&smem[4096 + ((kb * 2 + 1) * 64 + lane) * 8]);
#pragma unroll
            for (int f = 0; f < 4; ++f) {
                const short8v a2 = *reinterpret_cast<const short8v*>(&smem[Hbase + (rb + 16 * f + c) * 40 + 8 * gq]);
                Y[f][0] = __builtin_amdgcn_mfma_f32_16x16x32_bf16(a2, wva, Y[f][0], 0, 0, 0);
                Y[f][1] = __builtin_amdgcn_mfma_f32_16x16x32_bf16(a2, wvb, Y[f][1], 0, 0, 0);
            }
        }

        // ---- LayerNorm + store. Row r of D is lane-local; cols spread over
        //      the 16 lanes of each group -> shfl_xor reduce within group. ----
#pragma unroll
        for (int f = 0; f < 4; ++f) {
            float sm[4], sq[4];
#pragma unroll
            for (int r = 0; r < 4; ++r) {
                const float v0 = Y[f][0][r], v1 = Y[f][1][r];
                sm[r] = v0 + v1;
                sq[r] = v0 * v0 + v1 * v1;
            }
#pragma unroll
            for (int mask = 1; mask <= 8; mask <<= 1) {
#pragma unroll
                for (int r = 0; r < 4; ++r) {
                    sm[r] += __shfl_xor(sm[r], mask);
                    sq[r] += __shfl_xor(sq[r], mask);
                }
            }
#pragma unroll
            for (int r = 0; r < 4; ++r) {
                const float mu = sm[r] * (1.0f / 32.0f);
                const float var = sq[r] * (1.0f / 32.0f) - mu * mu;
                const float rs = rsqrtf(var + 1e-5f);
                float* op = io + (p0 + 16 * f + 4 * gq + r) * 32;
                op[c]      = (Y[f][0][r] - mu) * rs * gv[0] + bv[0];
                op[16 + c] = (Y[f][1][r] - mu) * rs * gv[1] + bv[1];
            }
        }
    }
}

extern "C" void kernel_launch(void* const* d_in, const int* in_sizes, int n_in,
                              void* d_out, int out_size, void* d_ws, size_t ws_size,
                              hipStream_t stream)
{
    const float* x    = (const float*)d_in[0];
    const float* wx   = (const float*)d_in[1];
    const float* wy   = (const float*)d_in[2];
    const float* wz   = (const float*)d_in[3];
    const float* w0   = (const float*)d_in[4];
    const float* b0   = (const float*)d_in[5];
    const float* w1   = (const float*)d_in[6];
    const float* b1   = (const float*)d_in[7];
    const float* ln_g = (const float*)d_in[8];
    const float* ln_b = (const float*)d_in[9];
    float* out = (float*)d_out;

    const int nblk = (4 * 64 * 64) / LINES;   // 4096

    spectral_axis_kernel<0, false><<<nblk, 256, 0, stream>>>(x, wx, out);
    spectral_axis_kernel<1, true ><<<nblk, 256, 0, stream>>>(x, wy, out);
    spectral_axis_kernel<2, true ><<<nblk, 256, 0, stream>>>(x, wz, out);

    // 1M points -> 16384 tiles of 64 -> 1024 blocks x 4 waves x 4 tiles
    ffn_ln_mfma_kernel<<<1024, 256, 0, stream>>>(out, w0, b0, w1, b1, ln_g, ln_b);
}

// Round 5
// 273.630 us; speedup vs baseline: 12.7257x; 1.7818x over previous
//
#include <hip/hip_runtime.h>
#include <math.h>

typedef __attribute__((ext_vector_type(8))) short short8v;
typedef __attribute__((ext_vector_type(4))) float float4v;

constexpr float THETA = 6.28318530717958647692f / 64.0f;  // 2*pi/64

// strides in floats for layout [b][m][n][z][c], c=32
constexpr int S_B = 64 * 64 * 64 * 32;
constexpr int S_M = 64 * 64 * 32;
constexpr int S_N = 64 * 32;
constexpr int S_Z = 32;

__device__ __forceinline__ unsigned short f2bf(float f) {
    unsigned int u = __builtin_bit_cast(unsigned int, f);
    u += 0x7FFFu + ((u >> 16) & 1u);
    return (unsigned short)(u >> 16);
}

// ---------------------------------------------------------------------------
// ws fragment layout (ushort units):
//   Wf: [ax 3][k 16][wt 2 (0=wr,1=wi)][rt 2][lane 64][e 8]   @ 0        (98304)
//   Tf: [jt 2][s 2][lane][e]                                  @ 98304    (2048)
//   Ti: [mt 4][lane][e]                                       @ 100352   (2048)
// Fragment k-slot convention everywhere: k = 8*(lane>>4) + e (A and B use the
// same bijection -> MFMA result independent of HW internal k ordering).
// ---------------------------------------------------------------------------
constexpr int WS_TF = 98304, WS_TI = 100352, WS_TOTAL = 102400;

__global__ __launch_bounds__(256)
void setup_frags(const float* __restrict__ wx, const float* __restrict__ wy,
                 const float* __restrict__ wz, unsigned short* __restrict__ W)
{
    int f0 = (blockIdx.x * 256 + threadIdx.x) * 4;
#pragma unroll
    for (int u = 0; u < 4; ++u) {
        int f = f0 + u;
        unsigned short v;
        if (f < WS_TF) {
            int ax = f >> 15, rem = f & 32767;
            int k = rem >> 11;
            int rem2 = rem & 2047;
            int wt = rem2 >> 10, rt = (rem2 >> 9) & 1, l = (rem2 >> 3) & 63, e = rem2 & 7;
            int o = 16 * rt + (l & 15), i = 8 * (l >> 4) + e;
            const float* w = (ax == 0) ? wx : ((ax == 1) ? wy : wz);
            v = f2bf(w[((i * 32 + o) * 16 + k) * 2 + wt]);
        } else if (f < WS_TI) {
            int rem = f - WS_TF;
            int jt = rem >> 10, s = (rem >> 9) & 1, l = (rem >> 3) & 63, e = rem & 7;
            int kk = l & 15, m = 32 * s + 8 * (l >> 4) + e;
            int jm = (kk * m) & 63;
            float ang = THETA * (float)jm;
            v = f2bf(jt == 0 ? cosf(ang) : sinf(ang));
        } else {
            int rem = f - WS_TI;
            int mt = rem >> 9, l = (rem >> 3) & 63, e = rem & 7;
            int mp = 16 * mt + (l & 15), r = 8 * (l >> 4) + e;
            int k = r & 15;
            float sk = (k == 0) ? (1.0f / 64.0f) : (2.0f / 64.0f);
            int jm = (k * mp) & 63;
            float ang = THETA * (float)jm;
            v = f2bf(r < 16 ? sk * cosf(ang) : -sk * sinf(ang));
        }
        W[f] = v;
    }
}

// AB: [t 2][k 16][line 16][i 32] bf16, XOR swizzle (bijective: 64B rows,
// key bit 6 pair-swaps adjacent lines since bit2(line^k) is invariant under
// line bit-0 flips).
__device__ __forceinline__ int ab_byte(int t, int k, int line, int i) {
    return ((((t * 16 + k) * 16 + line) * 64) + i * 2) ^ (((line ^ k) & 7) << 4);
}
// P7: [o 32][line 16][r pad 40] ushort, NO swizzle. Row pitch 80 B (16-aligned
// for b128 reads); round-4's XOR on this non-pow2 pitch was non-bijective.
__device__ __forceinline__ int p7i(int o, int line, int r) {
    return (o * 16 + line) * 40 + r;
}

// ---------------------------------------------------------------------------
// MFMA spectral conv along one axis. Block = 256 thr (4 waves), 16 lines.
// Stage F : F[i,j]   = sum_m x[m,i] trig(j,m)            (A=x direct-from-global)
// Stage Mx: PrT/PiT  per mode k, complex channel mixing  (A=weight frags from ws)
// Stage I : YT[o,m'] = PT[o,r] @ TiT[r,m']               (s_k folded into Ti)
// ---------------------------------------------------------------------------
template <int AXIS, bool ACCUM>
__global__ __launch_bounds__(256)
void spectral_mfma(const float* __restrict__ x,
                   const unsigned short* __restrict__ wf,
                   const unsigned short* __restrict__ tf,
                   const unsigned short* __restrict__ ti,
                   float* __restrict__ out)
{
    __shared__ __align__(16) unsigned short AB[16384];   // 32 KB
    __shared__ __align__(16) unsigned short P7[20480];   // 40 KB

    const int t = threadIdx.x, lane = t & 63, wave = t >> 6;
    const int gq = lane >> 4, c = lane & 15;
    constexpr int stride = (AXIS == 0) ? S_M : ((AXIS == 1) ? S_N : S_Z);
    const int l0 = blockIdx.x * 16;

    // ---- stage F ----
    short8v tfB[2][2];
#pragma unroll
    for (int jt = 0; jt < 2; ++jt)
#pragma unroll
        for (int s = 0; s < 2; ++s)
            tfB[jt][s] = *reinterpret_cast<const short8v*>(tf + ((jt * 2 + s) * 64 + lane) * 8);

    for (int li = 0; li < 4; ++li) {
        const int line = wave * 4 + li;
        const int l = l0 + line;
        const int b = l >> 12, p1 = (l >> 6) & 63, p2 = l & 63;
        long bs;
        if (AXIS == 0)      bs = (long)b * S_B + (long)p1 * S_N + (long)p2 * S_Z;
        else if (AXIS == 1) bs = (long)b * S_B + (long)p1 * S_M + (long)p2 * S_Z;
        else                bs = (long)b * S_B + (long)p1 * S_M + (long)p2 * S_N;

        float4v acc[2][2];
#pragma unroll
        for (int rt = 0; rt < 2; ++rt)
#pragma unroll
            for (int jt = 0; jt < 2; ++jt)
                acc[rt][jt] = float4v{0.f, 0.f, 0.f, 0.f};

#pragma unroll
        for (int rt = 0; rt < 2; ++rt) {
            const float* xp = x + bs + 16 * rt + c;
#pragma unroll
            for (int s = 0; s < 2; ++s) {
                short8v a;
#pragma unroll
                for (int e = 0; e < 8; ++e)
                    a[e] = (short)f2bf(xp[(long)(32 * s + 8 * gq + e) * stride]);
                acc[rt][0] = __builtin_amdgcn_mfma_f32_16x16x32_bf16(a, tfB[0][s], acc[rt][0], 0, 0, 0);
                acc[rt][1] = __builtin_amdgcn_mfma_f32_16x16x32_bf16(a, tfB[1][s], acc[rt][1], 0, 0, 0);
            }
        }
        // D rows = i = 16rt+4gq+r (4 consecutive channels), col j = 16jt+c -> (t=jt, k=c)
#pragma unroll
        for (int rt = 0; rt < 2; ++rt)
#pragma unroll
            for (int jt = 0; jt < 2; ++jt) {
                unsigned int lo = (unsigned int)f2bf(acc[rt][jt][0]) | ((unsigned int)f2bf(acc[rt][jt][1]) << 16);
                unsigned int hi = (unsigned int)f2bf(acc[rt][jt][2]) | ((unsigned int)f2bf(acc[rt][jt][3]) << 16);
                *reinterpret_cast<uint2*>(reinterpret_cast<char*>(AB) + ab_byte(jt, c, line, 16 * rt + 4 * gq)) =
                    make_uint2(lo, hi);
            }
    }
    __syncthreads();

    // ---- stage Mx: wave owns (t2 = Pr/Pi, rt = o-half) for all 16 modes.
    //      k processed in pairs so P7 writes are packed b32 (r-adjacent). ----
    {
        const int t2 = wave >> 1, rt = wave & 1;
        for (int k = 0; k < 16; k += 2) {
            float4v acc2[2];
#pragma unroll
            for (int kk = 0; kk < 2; ++kk) {
                const int kc = k + kk;
                short8v aT = *reinterpret_cast<const short8v*>(reinterpret_cast<const char*>(AB) + ab_byte(0, kc, c, 8 * gq));
                short8v bT = *reinterpret_cast<const short8v*>(reinterpret_cast<const char*>(AB) + ab_byte(1, kc, c, 8 * gq));
                const int w1t = t2 ? 1 : 0, w2t = t2 ? 0 : 1;
                short8v w1 = *reinterpret_cast<const short8v*>(wf + (((kc * 2 + w1t) * 2 + rt) * 64 + lane) * 8);
                short8v w2 = *reinterpret_cast<const short8v*>(wf + (((kc * 2 + w2t) * 2 + rt) * 64 + lane) * 8);
                if (t2) {
                    union { short8v s; unsigned int u[4]; } nb;
                    nb.s = bT;
#pragma unroll
                    for (int j = 0; j < 4; ++j) nb.u[j] ^= 0x80008000u;
                    bT = nb.s;
                }
                float4v a2 = float4v{0.f, 0.f, 0.f, 0.f};
                a2 = __builtin_amdgcn_mfma_f32_16x16x32_bf16(w1, aT, a2, 0, 0, 0);
                a2 = __builtin_amdgcn_mfma_f32_16x16x32_bf16(w2, bT, a2, 0, 0, 0);
                acc2[kk] = a2;
            }
            // D rows = o = 16rt+4gq+r, col = line = c; pack (k, k+1) per r.
#pragma unroll
            for (int r = 0; r < 4; ++r) {
                unsigned int u = (unsigned int)f2bf(acc2[0][r]) | ((unsigned int)f2bf(acc2[1][r]) << 16);
                *reinterpret_cast<unsigned int*>(&P7[p7i(16 * rt + 4 * gq + r, c, 16 * t2 + k)]) = u;
            }
        }
    }
    __syncthreads();

    // ---- stage I ----
    short8v tiB[4];
#pragma unroll
    for (int mt = 0; mt < 4; ++mt)
        tiB[mt] = *reinterpret_cast<const short8v*>(ti + (mt * 64 + lane) * 8);

    for (int li = 0; li < 4; ++li) {
        const int line = wave * 4 + li;
        const int l = l0 + line;
        const int b = l >> 12, p1 = (l >> 6) & 63, p2 = l & 63;
        long bs;
        if (AXIS == 0)      bs = (long)b * S_B + (long)p1 * S_N + (long)p2 * S_Z;
        else if (AXIS == 1) bs = (long)b * S_B + (long)p1 * S_M + (long)p2 * S_Z;
        else                bs = (long)b * S_B + (long)p1 * S_M + (long)p2 * S_N;

        short8v pA[2];
        pA[0] = *reinterpret_cast<const short8v*>(&P7[p7i(c,      line, 8 * gq)]);
        pA[1] = *reinterpret_cast<const short8v*>(&P7[p7i(16 + c, line, 8 * gq)]);

#pragma unroll
        for (int rt = 0; rt < 2; ++rt)
#pragma unroll
            for (int mt = 0; mt < 4; ++mt) {
                float4v acc = float4v{0.f, 0.f, 0.f, 0.f};
                acc = __builtin_amdgcn_mfma_f32_16x16x32_bf16(pA[rt], tiB[mt], acc, 0, 0, 0);
                // D rows = o = 16rt+4gq+r (4 consecutive channels), col m' = 16mt+c
                float* op = out + bs + (long)(16 * mt + c) * stride + 16 * rt + 4 * gq;
                if (ACCUM) {
                    float4 old = *reinterpret_cast<const float4*>(op);
                    old.x += acc[0]; old.y += acc[1]; old.z += acc[2]; old.w += acc[3];
                    *reinterpret_cast<float4*>(op) = old;
                } else {
                    *reinterpret_cast<float4*>(op) = make_float4(acc[0], acc[1], acc[2], acc[3]);
                }
            }
    }
}

// ---------------------------------------------------------------------------
// FFN (32 -> 128 ReLU -> 32) + LayerNorm via bf16 MFMA, in place (round 3).
// ---------------------------------------------------------------------------
__global__ __launch_bounds__(256)
void ffn_ln_mfma_kernel(float* __restrict__ io,
                        const float* __restrict__ w0, const float* __restrict__ b0,
                        const float* __restrict__ w1, const float* __restrict__ b1,
                        const float* __restrict__ g,  const float* __restrict__ bb)
{
    __shared__ unsigned short smem[28672];

    const int t = threadIdx.x;
    const int lane = t & 63, wave = t >> 6;
    const int gq = lane >> 4, c = lane & 15;

    for (int s = t; s < 512; s += 256) {
        const int n = s >> 6, ln = s & 63, g2 = ln >> 4, c2 = ln & 15;
        const int kb = n >> 1, nn = n & 1;
        short8v v0, v1;
#pragma unroll
        for (int e = 0; e < 8; ++e) {
            v0[e] = (short)f2bf(w0[(8 * g2 + e) * 128 + n * 16 + c2]);
            v1[e] = (short)f2bf(w1[(32 * kb + 8 * g2 + e) * 32 + nn * 16 + c2]);
        }
        *reinterpret_cast<short8v*>(&smem[s * 8])        = v0;
        *reinterpret_cast<short8v*>(&smem[4096 + s * 8]) = v1;
    }
    __syncthreads();

    float b0v[8], b1v[2], gv[2], bv[2];
#pragma unroll
    for (int n = 0; n < 8; ++n) b0v[n] = b0[n * 16 + c];
#pragma unroll
    for (int n = 0; n < 2; ++n) { b1v[n] = b1[n * 16 + c]; gv[n] = g[n * 16 + c]; bv[n] = bb[n * 16 + c]; }

    const int Hbase = 8192 + wave * 5120;

    for (int ti = 0; ti < 4; ++ti) {
        const int tile = (blockIdx.x * 4 + wave) * 4 + ti;
        const long p0 = (long)tile * 64;
        float* pio = io + p0 * 32;

        short8v af[4];
#pragma unroll
        for (int f = 0; f < 4; ++f) {
            const float* sp = pio + (16 * f + c) * 32 + 8 * gq;
            float4 lo = *reinterpret_cast<const float4*>(sp);
            float4 hi = *reinterpret_cast<const float4*>(sp + 4);
            af[f][0] = (short)f2bf(lo.x); af[f][1] = (short)f2bf(lo.y);
            af[f][2] = (short)f2bf(lo.z); af[f][3] = (short)f2bf(lo.w);
            af[f][4] = (short)f2bf(hi.x); af[f][5] = (short)f2bf(hi.y);
            af[f][6] = (short)f2bf(hi.z); af[f][7] = (short)f2bf(hi.w);
        }

        float4v Y[4][2];
#pragma unroll
        for (int f = 0; f < 4; ++f)
#pragma unroll
            for (int n = 0; n < 2; ++n)
                Y[f][n] = float4v{b1v[n], b1v[n], b1v[n], b1v[n]};

#pragma unroll
        for (int kb = 0; kb < 4; ++kb) {
            const int rb = (kb & 1) * 64;
#pragma unroll
            for (int nn = 0; nn < 2; ++nn) {
                const int n = 2 * kb + nn;
                const short8v wv = *reinterpret_cast<const short8v*>(&smem[(n * 64 + lane) * 8]);
#pragma unroll
                for (int f = 0; f < 4; ++f) {
                    float4v hacc = float4v{b0v[n], b0v[n], b0v[n], b0v[n]};
                    hacc = __builtin_amdgcn_mfma_f32_16x16x32_bf16(af[f], wv, hacc, 0, 0, 0);
#pragma unroll
                    for (int r = 0; r < 4; ++r) {
                        const float hv = fmaxf(hacc[r], 0.0f);
                        smem[Hbase + (rb + 16 * f + 4 * gq + r) * 40 + nn * 16 + c] = f2bf(hv);
                    }
                }
            }
            const short8v wva = *reinterpret_cast<const short8v*>(&smem[4096 + ((kb * 2 + 0) * 64 + lane) * 8]);
            const short8v wvb = *reinterpret_cast<const short8v*>(&smem[4096 + ((kb * 2 + 1) * 64 + lane) * 8]);
#pragma unroll
            for (int f = 0; f < 4; ++f) {
                const short8v a2 = *reinterpret_cast<const short8v*>(&smem[Hbase + (rb + 16 * f + c) * 40 + 8 * gq]);
                Y[f][0] = __builtin_amdgcn_mfma_f32_16x16x32_bf16(a2, wva, Y[f][0], 0, 0, 0);
                Y[f][1] = __builtin_amdgcn_mfma_f32_16x16x32_bf16(a2, wvb, Y[f][1], 0, 0, 0);
            }
        }

#pragma unroll
        for (int f = 0; f < 4; ++f) {
            float sm[4], sq[4];
#pragma unroll
            for (int r = 0; r < 4; ++r) {
                const float v0 = Y[f][0][r], v1 = Y[f][1][r];
                sm[r] = v0 + v1;
                sq[r] = v0 * v0 + v1 * v1;
            }
#pragma unroll
            for (int mask = 1; mask <= 8; mask <<= 1) {
#pragma unroll
                for (int r = 0; r < 4; ++r) {
                    sm[r] += __shfl_xor(sm[r], mask);
                    sq[r] += __shfl_xor(sq[r], mask);
                }
            }
#pragma unroll
            for (int r = 0; r < 4; ++r) {
                const float mu = sm[r] * (1.0f / 32.0f);
                const float var = sq[r] * (1.0f / 32.0f) - mu * mu;
                const float rs = rsqrtf(var + 1e-5f);
                float* op = io + (p0 + 16 * f + 4 * gq + r) * 32;
                op[c]      = (Y[f][0][r] - mu) * rs * gv[0] + bv[0];
                op[16 + c] = (Y[f][1][r] - mu) * rs * gv[1] + bv[1];
            }
        }
    }
}

extern "C" void kernel_launch(void* const* d_in, const int* in_sizes, int n_in,
                              void* d_out, int out_size, void* d_ws, size_t ws_size,
                              hipStream_t stream)
{
    const float* x    = (const float*)d_in[0];
    const float* wx   = (const float*)d_in[1];
    const float* wy   = (const float*)d_in[2];
    const float* wz   = (const float*)d_in[3];
    const float* w0   = (const float*)d_in[4];
    const float* b0   = (const float*)d_in[5];
    const float* w1   = (const float*)d_in[6];
    const float* b1   = (const float*)d_in[7];
    const float* ln_g = (const float*)d_in[8];
    const float* ln_b = (const float*)d_in[9];
    float* out = (float*)d_out;

    unsigned short* wsf = (unsigned short*)d_ws;

    setup_frags<<<100, 256, 0, stream>>>(wx, wy, wz, wsf);

    spectral_mfma<0, false><<<1024, 256, 0, stream>>>(x, wsf + 0 * 32768, wsf + WS_TF, wsf + WS_TI, out);
    spectral_mfma<1, true ><<<1024, 256, 0, stream>>>(x, wsf + 1 * 32768, wsf + WS_TF, wsf + WS_TI, out);
    spectral_mfma<2, true ><<<1024, 256, 0, stream>>>(x, wsf + 2 * 32768, wsf + WS_TF, wsf + WS_TI, out);

    ffn_ln_mfma_kernel<<<1024, 256, 0, stream>>>(out, w0, b0, w1, b1, ln_g, ln_b);
}

// Round 6
// 260.818 us; speedup vs baseline: 13.3509x; 1.0491x over previous
//
#include <hip/hip_runtime.h>
#include <math.h>

typedef __attribute__((ext_vector_type(8))) short short8v;
typedef __attribute__((ext_vector_type(4))) float float4v;

constexpr float THETA = 6.28318530717958647692f / 64.0f;  // 2*pi/64

// strides in floats for layout [b][m][n][z][c], c=32
constexpr int S_B = 64 * 64 * 64 * 32;
constexpr int S_M = 64 * 64 * 32;
constexpr int S_N = 64 * 32;
constexpr int S_Z = 32;

__device__ __forceinline__ unsigned short f2bf(float f) {
    unsigned int u = __builtin_bit_cast(unsigned int, f);
    u += 0x7FFFu + ((u >> 16) & 1u);
    return (unsigned short)(u >> 16);
}

// ---------------------------------------------------------------------------
// ws fragment layout (ushort units) — unchanged from round 5:
//   Wf: [ax 3][k 16][wt 2 (0=wr,1=wi)][rt 2][lane 64][e 8]   @ 0        (98304)
//   Tf: [jt 2][s 2][lane][e]                                  @ 98304    (2048)
//   Ti: [mt 4][lane][e]                                       @ 100352   (2048)
// k-slot convention everywhere: k = 8*(lane>>4) + e (A and B share bijection).
// ---------------------------------------------------------------------------
constexpr int WS_TF = 98304, WS_TI = 100352, WS_TOTAL = 102400;

__global__ __launch_bounds__(256)
void setup_frags(const float* __restrict__ wx, const float* __restrict__ wy,
                 const float* __restrict__ wz, unsigned short* __restrict__ W)
{
    int f0 = (blockIdx.x * 256 + threadIdx.x) * 4;
#pragma unroll
    for (int u = 0; u < 4; ++u) {
        int f = f0 + u;
        if (f >= WS_TOTAL) continue;
        unsigned short v;
        if (f < WS_TF) {
            int ax = f >> 15, rem = f & 32767;
            int k = rem >> 11;
            int rem2 = rem & 2047;
            int wt = rem2 >> 10, rt = (rem2 >> 9) & 1, l = (rem2 >> 3) & 63, e = rem2 & 7;
            int o = 16 * rt + (l & 15), i = 8 * (l >> 4) + e;
            const float* w = (ax == 0) ? wx : ((ax == 1) ? wy : wz);
            v = f2bf(w[((i * 32 + o) * 16 + k) * 2 + wt]);
        } else if (f < WS_TI) {
            int rem = f - WS_TF;
            int jt = rem >> 10, s = (rem >> 9) & 1, l = (rem >> 3) & 63, e = rem & 7;
            int kk = l & 15, m = 32 * s + 8 * (l >> 4) + e;
            int jm = (kk * m) & 63;
            float ang = THETA * (float)jm;
            v = f2bf(jt == 0 ? cosf(ang) : sinf(ang));
        } else {
            int rem = f - WS_TI;
            int mt = rem >> 9, l = (rem >> 3) & 63, e = rem & 7;
            int mp = 16 * mt + (l & 15), r = 8 * (l >> 4) + e;
            int k = r & 15;
            float sk = (k == 0) ? (1.0f / 64.0f) : (2.0f / 64.0f);
            int jm = (k * mp) & 63;
            float ang = THETA * (float)jm;
            v = f2bf(r < 16 ? sk * cosf(ang) : -sk * sinf(ang));
        }
        W[f] = v;
    }
}

// AB: [t 2][k 16][line 8][i 32] bf16, 64-B rows, XOR swizzle (bijective:
// addr bit6 = line bit0; key bit2 = (line^k) bit2 is recoverable from
// addr bits 7-8 + k, so the map inverts cleanly).
constexpr int AB_SHORTS = 8192;   // 16 KB
__device__ __forceinline__ int ab8(int t, int k, int line, int i) {
    return ((((t * 16 + k) * 8 + line) * 64) + i * 2) ^ (((line ^ k) & 7) << 4);
}
// P: [line 8][o 32][r 40] ushort, line stride padded to 1288 shorts so the
// o-stride (80 B) and line-stride (2576 B) are NOT 0 mod 128 B -> reads and
// writes spread over bank quads (old layout was a 16-way conflict).
constexpr int P_LS = 1288;
constexpr int P_SHORTS = 8 * P_LS;  // 10304, ~20.1 KB
__device__ __forceinline__ int p8(int line, int o, int r) {
    return line * P_LS + o * 40 + r;
}

// ---- stage F: forward transform, per wave 2 lines, A = x direct from global ----
template <int STRIDE>
__device__ __forceinline__ void stageF(const float* __restrict__ x,
                                       const long* base2,
                                       const unsigned short* __restrict__ tf,
                                       unsigned short* __restrict__ AB,
                                       int lane, int wave)
{
    const int gq = lane >> 4, c = lane & 15;
    short8v tfB[2][2];
#pragma unroll
    for (int jt = 0; jt < 2; ++jt)
#pragma unroll
        for (int s = 0; s < 2; ++s)
            tfB[jt][s] = *reinterpret_cast<const short8v*>(tf + ((jt * 2 + s) * 64 + lane) * 8);

#pragma unroll
    for (int li = 0; li < 2; ++li) {
        const int line = wave * 2 + li;
        float4v acc[2][2];
#pragma unroll
        for (int rt = 0; rt < 2; ++rt)
#pragma unroll
            for (int jt = 0; jt < 2; ++jt)
                acc[rt][jt] = float4v{0.f, 0.f, 0.f, 0.f};

#pragma unroll
        for (int rt = 0; rt < 2; ++rt) {
            const float* xp = x + base2[li] + 16 * rt + c;
#pragma unroll
            for (int s = 0; s < 2; ++s) {
                short8v a;
#pragma unroll
                for (int e = 0; e < 8; ++e)
                    a[e] = (short)f2bf(xp[(long)(32 * s + 8 * gq + e) * STRIDE]);
                acc[rt][0] = __builtin_amdgcn_mfma_f32_16x16x32_bf16(a, tfB[0][s], acc[rt][0], 0, 0, 0);
                acc[rt][1] = __builtin_amdgcn_mfma_f32_16x16x32_bf16(a, tfB[1][s], acc[rt][1], 0, 0, 0);
            }
        }
#pragma unroll
        for (int rt = 0; rt < 2; ++rt)
#pragma unroll
            for (int jt = 0; jt < 2; ++jt) {
                unsigned int lo = (unsigned int)f2bf(acc[rt][jt][0]) | ((unsigned int)f2bf(acc[rt][jt][1]) << 16);
                unsigned int hi = (unsigned int)f2bf(acc[rt][jt][2]) | ((unsigned int)f2bf(acc[rt][jt][3]) << 16);
                *reinterpret_cast<uint2*>(reinterpret_cast<char*>(AB) + ab8(jt, c, line, 16 * rt + 4 * gq)) =
                    make_uint2(lo, hi);
            }
    }
}

// ---- stage Mx: complex channel mixing; wave owns (Pr/Pi, o-half) quadrant ----
__device__ __forceinline__ void stageMx(const unsigned short* __restrict__ wf,
                                        const unsigned short* __restrict__ AB,
                                        unsigned short* __restrict__ P,
                                        int lane, int wave)
{
    const int gq = lane >> 4, c = lane & 15;
    const int t2 = wave >> 1, rt = wave & 1, lc = c & 7;
    for (int k = 0; k < 16; k += 2) {
        float4v acc2[2];
#pragma unroll
        for (int kk = 0; kk < 2; ++kk) {
            const int kc = k + kk;
            short8v aT = *reinterpret_cast<const short8v*>(reinterpret_cast<const char*>(AB) + ab8(0, kc, lc, 8 * gq));
            short8v bT = *reinterpret_cast<const short8v*>(reinterpret_cast<const char*>(AB) + ab8(1, kc, lc, 8 * gq));
            const int w1t = t2 ? 1 : 0, w2t = t2 ? 0 : 1;
            short8v w1 = *reinterpret_cast<const short8v*>(wf + (((kc * 2 + w1t) * 2 + rt) * 64 + lane) * 8);
            short8v w2 = *reinterpret_cast<const short8v*>(wf + (((kc * 2 + w2t) * 2 + rt) * 64 + lane) * 8);
            if (t2) {
                union { short8v s; unsigned int u[4]; } nb;
                nb.s = bT;
#pragma unroll
                for (int j = 0; j < 4; ++j) nb.u[j] ^= 0x80008000u;
                bT = nb.s;
            }
            float4v a2 = float4v{0.f, 0.f, 0.f, 0.f};
            a2 = __builtin_amdgcn_mfma_f32_16x16x32_bf16(w1, aT, a2, 0, 0, 0);
            a2 = __builtin_amdgcn_mfma_f32_16x16x32_bf16(w2, bT, a2, 0, 0, 0);
            acc2[kk] = a2;
        }
        // D: col = line = c (only c<8 valid), rows o = 16rt+4gq+r; pack k-pairs.
        if (c < 8) {
#pragma unroll
            for (int r = 0; r < 4; ++r) {
                unsigned int u = (unsigned int)f2bf(acc2[0][r]) | ((unsigned int)f2bf(acc2[1][r]) << 16);
                *reinterpret_cast<unsigned int*>(&P[p8(c, 16 * rt + 4 * gq + r, 16 * t2 + k)]) = u;
            }
        }
    }
}

// ---------------------------------------------------------------------------
// Non-fused spectral kernel (axes M, N). 8 lines/block, ~37 KB LDS -> 4 blk/CU.
// ---------------------------------------------------------------------------
template <int AXIS, bool ACCUM>
__global__ __launch_bounds__(256)
void spectral_mfma(const float* __restrict__ x,
                   const unsigned short* __restrict__ wf,
                   const unsigned short* __restrict__ tf,
                   const unsigned short* __restrict__ ti,
                   float* __restrict__ out)
{
    __shared__ __align__(16) unsigned short AB[AB_SHORTS];
    __shared__ __align__(16) unsigned short P[P_SHORTS];

    const int t = threadIdx.x, lane = t & 63, wave = t >> 6;
    const int gq = lane >> 4, c = lane & 15;
    constexpr int stride = (AXIS == 0) ? S_M : S_N;
    const int l0 = blockIdx.x * 8;

    long base2[2];
#pragma unroll
    for (int li = 0; li < 2; ++li) {
        int l = l0 + wave * 2 + li;
        int b = l >> 12, p1 = (l >> 6) & 63, p2 = l & 63;
        base2[li] = (AXIS == 0)
            ? (long)b * S_B + (long)p1 * S_N + (long)p2 * S_Z
            : (long)b * S_B + (long)p1 * S_M + (long)p2 * S_Z;
    }

    stageF<stride>(x, base2, tf, AB, lane, wave);
    __syncthreads();
    stageMx(wf, AB, P, lane, wave);
    __syncthreads();

    // ---- stage I + global write ----
    short8v tiB[4];
#pragma unroll
    for (int mt = 0; mt < 4; ++mt)
        tiB[mt] = *reinterpret_cast<const short8v*>(ti + (mt * 64 + lane) * 8);

#pragma unroll
    for (int li = 0; li < 2; ++li) {
        const int line = wave * 2 + li;
        short8v pA[2];
        pA[0] = *reinterpret_cast<const short8v*>(&P[p8(line, c, 8 * gq)]);
        pA[1] = *reinterpret_cast<const short8v*>(&P[p8(line, 16 + c, 8 * gq)]);
#pragma unroll
        for (int rt = 0; rt < 2; ++rt)
#pragma unroll
            for (int mt = 0; mt < 4; ++mt) {
                float4v acc = float4v{0.f, 0.f, 0.f, 0.f};
                acc = __builtin_amdgcn_mfma_f32_16x16x32_bf16(pA[rt], tiB[mt], acc, 0, 0, 0);
                float* op = out + base2[li] + (long)(16 * mt + c) * stride + 16 * rt + 4 * gq;
                if (ACCUM) {
                    float4 old = *reinterpret_cast<const float4*>(op);
                    old.x += acc[0]; old.y += acc[1]; old.z += acc[2]; old.w += acc[3];
                    *reinterpret_cast<float4*>(op) = old;
                } else {
                    *reinterpret_cast<float4*>(op) = make_float4(acc[0], acc[1], acc[2], acc[3]);
                }
            }
    }
}

// ---------------------------------------------------------------------------
// Fused axis-Z spectral + FFN + LayerNorm. 8 lines/block; each line is one
// 64-point FFN tile. LDS regions (shorts), strictly barrier-separated reuse:
//   [0,8192)      AB  -> (after Mx)   FFN weight fragments
//   [8192,18496)  P   -> (after I)    per-wave H buffers (4 x 2560)
//   [18496,38976) S   = sum tile [line 8][pt 64][ch pad 40] bf16
// ---------------------------------------------------------------------------
__global__ __launch_bounds__(256)
void spectral_fused(const float* __restrict__ x,
                    const unsigned short* __restrict__ wf,
                    const unsigned short* __restrict__ tf,
                    const unsigned short* __restrict__ ti,
                    const float* __restrict__ w0, const float* __restrict__ b0,
                    const float* __restrict__ w1, const float* __restrict__ b1,
                    const float* __restrict__ g,  const float* __restrict__ bb,
                    float* __restrict__ out)
{
    __shared__ __align__(16) unsigned short sm[38976];
    constexpr int OP = 8192, OS = 18496;

    const int t = threadIdx.x, lane = t & 63, wave = t >> 6;
    const int gq = lane >> 4, c = lane & 15;
    const int l0 = blockIdx.x * 8;

    long base2[2];
#pragma unroll
    for (int li = 0; li < 2; ++li) {
        int l = l0 + wave * 2 + li;
        int b = l >> 12, p1 = (l >> 6) & 63, p2 = l & 63;
        base2[li] = (long)b * S_B + (long)p1 * S_M + (long)p2 * S_N;
    }

    // hoisted FFN per-lane constants
    float b0v[8], b1v[2], gv[2], bvv[2];
#pragma unroll
    for (int n = 0; n < 8; ++n) b0v[n] = b0[n * 16 + c];
#pragma unroll
    for (int n = 0; n < 2; ++n) { b1v[n] = b1[n * 16 + c]; gv[n] = g[n * 16 + c]; bvv[n] = bb[n * 16 + c]; }

    stageF<S_Z>(x, base2, tf, sm, lane, wave);
    __syncthreads();
    stageMx(wf, sm, sm + OP, lane, wave);
    __syncthreads();

    // ---- FFN weight fragments into dead AB region ----
    for (int s = t; s < 512; s += 256) {
        const int n = s >> 6, ln = s & 63, g2 = ln >> 4, c2 = ln & 15;
        const int kb = n >> 1, nn = n & 1;
        short8v v0, v1;
#pragma unroll
        for (int e = 0; e < 8; ++e) {
            v0[e] = (short)f2bf(w0[(8 * g2 + e) * 128 + n * 16 + c2]);
            v1[e] = (short)f2bf(w1[(32 * kb + 8 * g2 + e) * 32 + nn * 16 + c2]);
        }
        *reinterpret_cast<short8v*>(&sm[s * 8])        = v0;
        *reinterpret_cast<short8v*>(&sm[4096 + s * 8]) = v1;
    }

    // ---- stage I: S = out-partial(xx+xy) + axis-z result, bf16 in LDS ----
    short8v tiB[4];
#pragma unroll
    for (int mt = 0; mt < 4; ++mt)
        tiB[mt] = *reinterpret_cast<const short8v*>(ti + (mt * 64 + lane) * 8);

#pragma unroll
    for (int li = 0; li < 2; ++li) {
        const int line = wave * 2 + li;
        const long bs = base2[li];
        short8v pA[2];
        pA[0] = *reinterpret_cast<const short8v*>(&sm[OP + p8(line, c, 8 * gq)]);
        pA[1] = *reinterpret_cast<const short8v*>(&sm[OP + p8(line, 16 + c, 8 * gq)]);
#pragma unroll
        for (int rt = 0; rt < 2; ++rt)
#pragma unroll
            for (int mt = 0; mt < 4; ++mt) {
                float4v acc = float4v{0.f, 0.f, 0.f, 0.f};
                acc = __builtin_amdgcn_mfma_f32_16x16x32_bf16(pA[rt], tiB[mt], acc, 0, 0, 0);
                const float* op = out + bs + (long)(16 * mt + c) * S_Z + 16 * rt + 4 * gq;
                float4 old = *reinterpret_cast<const float4*>(op);
                const float v0 = old.x + acc[0], v1 = old.y + acc[1];
                const float v2 = old.z + acc[2], v3 = old.w + acc[3];
                const int si = OS + (line * 64 + 16 * mt + c) * 40 + 16 * rt + 4 * gq;
                *reinterpret_cast<unsigned int*>(&sm[si])     = (unsigned int)f2bf(v0) | ((unsigned int)f2bf(v1) << 16);
                *reinterpret_cast<unsigned int*>(&sm[si + 2]) = (unsigned int)f2bf(v2) | ((unsigned int)f2bf(v3) << 16);
            }
    }
    __syncthreads();

    // ---- FFN + LN per wave (2 line-tiles), H in dead P region ----
    const int Hb = OP + wave * 2560;
#pragma unroll
    for (int li = 0; li < 2; ++li) {
        const int line = wave * 2 + li;
        const long bs = base2[li];

        short8v af[4];
#pragma unroll
        for (int f = 0; f < 4; ++f)
            af[f] = *reinterpret_cast<const short8v*>(&sm[OS + (line * 64 + 16 * f + c) * 40 + 8 * gq]);

        float4v Y[4][2];
#pragma unroll
        for (int f = 0; f < 4; ++f)
#pragma unroll
            for (int n = 0; n < 2; ++n)
                Y[f][n] = float4v{b1v[n], b1v[n], b1v[n], b1v[n]};

#pragma unroll
        for (int kb = 0; kb < 4; ++kb) {
#pragma unroll
            for (int nn = 0; nn < 2; ++nn) {
                const int n = 2 * kb + nn;
                const short8v wv = *reinterpret_cast<const short8v*>(&sm[(n * 64 + lane) * 8]);
#pragma unroll
                for (int f = 0; f < 4; ++f) {
                    float4v hacc = float4v{b0v[n], b0v[n], b0v[n], b0v[n]};
                    hacc = __builtin_amdgcn_mfma_f32_16x16x32_bf16(af[f], wv, hacc, 0, 0, 0);
#pragma unroll
                    for (int r = 0; r < 4; ++r)
                        sm[Hb + (16 * f + 4 * gq + r) * 40 + nn * 16 + c] = f2bf(fmaxf(hacc[r], 0.f));
                }
            }
            const short8v wva = *reinterpret_cast<const short8v*>(&sm[4096 + ((kb * 2 + 0) * 64 + lane) * 8]);
            const short8v wvb = *reinterpret_cast<const short8v*>(&sm[4096 + ((kb * 2 + 1) * 64 + lane) * 8]);
#pragma unroll
            for (int f = 0; f < 4; ++f) {
                const short8v a2 = *reinterpret_cast<const short8v*>(&sm[Hb + (16 * f + c) * 40 + 8 * gq]);
                Y[f][0] = __builtin_amdgcn_mfma_f32_16x16x32_bf16(a2, wva, Y[f][0], 0, 0, 0);
                Y[f][1] = __builtin_amdgcn_mfma_f32_16x16x32_bf16(a2, wvb, Y[f][1], 0, 0, 0);
            }
        }

#pragma unroll
        for (int f = 0; f < 4; ++f) {
            float smv[4], sq[4];
#pragma unroll
            for (int r = 0; r < 4; ++r) {
                const float v0 = Y[f][0][r], v1 = Y[f][1][r];
                smv[r] = v0 + v1;
                sq[r]  = v0 * v0 + v1 * v1;
            }
#pragma unroll
            for (int mask = 1; mask <= 8; mask <<= 1) {
#pragma unroll
                for (int r = 0; r < 4; ++r) {
                    smv[r] += __shfl_xor(smv[r], mask);
                    sq[r]  += __shfl_xor(sq[r], mask);
                }
            }
#pragma unroll
            for (int r = 0; r < 4; ++r) {
                const float mu = smv[r] * (1.0f / 32.0f);
                const float var = sq[r] * (1.0f / 32.0f) - mu * mu;
                const float rs = rsqrtf(var + 1e-5f);
                float* op = out + bs + (long)(16 * f + 4 * gq + r) * 32;
                op[c]      = (Y[f][0][r] - mu) * rs * gv[0] + bvv[0];
                op[16 + c] = (Y[f][1][r] - mu) * rs * gv[1] + bvv[1];
            }
        }
    }
}

extern "C" void kernel_launch(void* const* d_in, const int* in_sizes, int n_in,
                              void* d_out, int out_size, void* d_ws, size_t ws_size,
                              hipStream_t stream)
{
    const float* x    = (const float*)d_in[0];
    const float* wx   = (const float*)d_in[1];
    const float* wy   = (const float*)d_in[2];
    const float* wz   = (const float*)d_in[3];
    const float* w0   = (const float*)d_in[4];
    const float* b0   = (const float*)d_in[5];
    const float* w1   = (const float*)d_in[6];
    const float* b1   = (const float*)d_in[7];
    const float* ln_g = (const float*)d_in[8];
    const float* ln_b = (const float*)d_in[9];
    float* out = (float*)d_out;

    unsigned short* wsf = (unsigned short*)d_ws;

    setup_frags<<<100, 256, 0, stream>>>(wx, wy, wz, wsf);

    // 16384 lines per axis / 8 per block = 2048 blocks
    spectral_mfma<0, false><<<2048, 256, 0, stream>>>(x, wsf + 0 * 32768, wsf + WS_TF, wsf + WS_TI, out);
    spectral_mfma<1, true ><<<2048, 256, 0, stream>>>(x, wsf + 1 * 32768, wsf + WS_TF, wsf + WS_TI, out);
    spectral_fused<<<2048, 256, 0, stream>>>(x, wsf + 2 * 32768, wsf + WS_TF, wsf + WS_TI,
                                             w0, b0, w1, b1, ln_g, ln_b, out);
}

// Round 7
// 229.097 us; speedup vs baseline: 15.1994x; 1.1385x over previous
//
#include <hip/hip_runtime.h>
#include <math.h>

typedef __attribute__((ext_vector_type(8))) short short8v;
typedef __attribute__((ext_vector_type(4))) float float4v;

constexpr float THETA = 6.28318530717958647692f / 64.0f;  // 2*pi/64

// strides in floats for layout [b][m][n][z][c], c=32
constexpr int S_B = 64 * 64 * 64 * 32;
constexpr int S_M = 64 * 64 * 32;
constexpr int S_N = 64 * 32;
constexpr int S_Z = 32;

__device__ __forceinline__ unsigned short f2bf(float f) {
    unsigned int u = __builtin_bit_cast(unsigned int, f);
    u += 0x7FFFu + ((u >> 16) & 1u);
    return (unsigned short)(u >> 16);
}
__device__ __forceinline__ float bf2f(unsigned int h) {
    return __builtin_bit_cast(float, h << 16);
}

// ---------------------------------------------------------------------------
// ws fragment layout (ushort units) — unchanged from round 5/6:
//   Wf: [ax 3][k 16][wt 2 (0=wr,1=wi)][rt 2][lane 64][e 8]   @ 0        (98304)
//   Tf: [jt 2][s 2][lane][e]                                  @ 98304    (2048)
//   Ti: [mt 4][lane][e]                                       @ 100352   (2048)
// k-slot convention everywhere: k = 8*(lane>>4) + e (A and B share bijection).
// ---------------------------------------------------------------------------
constexpr int WS_TF = 98304, WS_TI = 100352, WS_TOTAL = 102400;

__global__ __launch_bounds__(256)
void setup_frags(const float* __restrict__ wx, const float* __restrict__ wy,
                 const float* __restrict__ wz, unsigned short* __restrict__ W)
{
    int f0 = (blockIdx.x * 256 + threadIdx.x) * 4;
#pragma unroll
    for (int u = 0; u < 4; ++u) {
        int f = f0 + u;
        if (f >= WS_TOTAL) continue;
        unsigned short v;
        if (f < WS_TF) {
            int ax = f >> 15, rem = f & 32767;
            int k = rem >> 11;
            int rem2 = rem & 2047;
            int wt = rem2 >> 10, rt = (rem2 >> 9) & 1, l = (rem2 >> 3) & 63, e = rem2 & 7;
            int o = 16 * rt + (l & 15), i = 8 * (l >> 4) + e;
            const float* w = (ax == 0) ? wx : ((ax == 1) ? wy : wz);
            v = f2bf(w[((i * 32 + o) * 16 + k) * 2 + wt]);
        } else if (f < WS_TI) {
            int rem = f - WS_TF;
            int jt = rem >> 10, s = (rem >> 9) & 1, l = (rem >> 3) & 63, e = rem & 7;
            int kk = l & 15, m = 32 * s + 8 * (l >> 4) + e;
            int jm = (kk * m) & 63;
            float ang = THETA * (float)jm;
            v = f2bf(jt == 0 ? cosf(ang) : sinf(ang));
        } else {
            int rem = f - WS_TI;
            int mt = rem >> 9, l = (rem >> 3) & 63, e = rem & 7;
            int mp = 16 * mt + (l & 15), r = 8 * (l >> 4) + e;
            int k = r & 15;
            float sk = (k == 0) ? (1.0f / 64.0f) : (2.0f / 64.0f);
            int jm = (k * mp) & 63;
            float ang = THETA * (float)jm;
            v = f2bf(r < 16 ? sk * cosf(ang) : -sk * sinf(ang));
        }
        W[f] = v;
    }
}

// AB: [t 2][k 16][line 4][i 32] bf16, 64-B rows, XOR swizzle (bijective: key
// bits 4-5 depend only on higher addr bits / k; bit6 ^= const(k)).
constexpr int AB_SHORTS = 4096;   // 8 KB
__device__ __forceinline__ int ab4(int t, int k, int line, int i) {
    return ((((t * 16 + k) * 4 + line) * 64) + i * 2) ^ (((line ^ k) & 7) << 4);
}
// P: [line 4][o 32][r 40] ushort, line stride 1288 (strides not 0 mod 128 B).
constexpr int P_LS = 1288;
constexpr int P_SHORTS = 4 * P_LS;  // 5152
__device__ __forceinline__ int p4(int line, int o, int r) {
    return line * P_LS + o * 40 + r;
}

// ---- stage F: forward transform, 1 line per wave, A = x direct from global ----
template <int STRIDE>
__device__ __forceinline__ void stageF1(const float* __restrict__ x, long bs,
                                        const unsigned short* __restrict__ tf,
                                        unsigned short* __restrict__ AB,
                                        int lane, int line)
{
    const int gq = lane >> 4, c = lane & 15;
    short8v tfB[2][2];
#pragma unroll
    for (int jt = 0; jt < 2; ++jt)
#pragma unroll
        for (int s = 0; s < 2; ++s)
            tfB[jt][s] = *reinterpret_cast<const short8v*>(tf + ((jt * 2 + s) * 64 + lane) * 8);

    float4v acc[2][2];
#pragma unroll
    for (int rt = 0; rt < 2; ++rt)
#pragma unroll
        for (int jt = 0; jt < 2; ++jt)
            acc[rt][jt] = float4v{0.f, 0.f, 0.f, 0.f};

#pragma unroll
    for (int rt = 0; rt < 2; ++rt) {
        const float* xp = x + bs + 16 * rt + c;
#pragma unroll
        for (int s = 0; s < 2; ++s) {
            short8v a;
#pragma unroll
            for (int e = 0; e < 8; ++e)
                a[e] = (short)f2bf(xp[(long)(32 * s + 8 * gq + e) * STRIDE]);
            acc[rt][0] = __builtin_amdgcn_mfma_f32_16x16x32_bf16(a, tfB[0][s], acc[rt][0], 0, 0, 0);
            acc[rt][1] = __builtin_amdgcn_mfma_f32_16x16x32_bf16(a, tfB[1][s], acc[rt][1], 0, 0, 0);
        }
    }
#pragma unroll
    for (int rt = 0; rt < 2; ++rt)
#pragma unroll
        for (int jt = 0; jt < 2; ++jt) {
            unsigned int lo = (unsigned int)f2bf(acc[rt][jt][0]) | ((unsigned int)f2bf(acc[rt][jt][1]) << 16);
            unsigned int hi = (unsigned int)f2bf(acc[rt][jt][2]) | ((unsigned int)f2bf(acc[rt][jt][3]) << 16);
            *reinterpret_cast<uint2*>(reinterpret_cast<char*>(AB) + ab4(jt, c, line, 16 * rt + 4 * gq)) =
                make_uint2(lo, hi);
        }
}

// ---- stage Mx: complex channel mixing; wave owns (Pr/Pi, o-half) quadrant ----
__device__ __forceinline__ void stageMx4(const unsigned short* __restrict__ wf,
                                         const unsigned short* __restrict__ AB,
                                         unsigned short* __restrict__ P,
                                         int lane, int wave)
{
    const int gq = lane >> 4, c = lane & 15;
    const int t2 = wave >> 1, rt = wave & 1, lc = c & 3;
    for (int k = 0; k < 16; k += 2) {
        float4v acc2[2];
#pragma unroll
        for (int kk = 0; kk < 2; ++kk) {
            const int kc = k + kk;
            short8v aT = *reinterpret_cast<const short8v*>(reinterpret_cast<const char*>(AB) + ab4(0, kc, lc, 8 * gq));
            short8v bT = *reinterpret_cast<const short8v*>(reinterpret_cast<const char*>(AB) + ab4(1, kc, lc, 8 * gq));
            const int w1t = t2 ? 1 : 0, w2t = t2 ? 0 : 1;
            short8v w1 = *reinterpret_cast<const short8v*>(wf + (((kc * 2 + w1t) * 2 + rt) * 64 + lane) * 8);
            short8v w2 = *reinterpret_cast<const short8v*>(wf + (((kc * 2 + w2t) * 2 + rt) * 64 + lane) * 8);
            if (t2) {
                union { short8v s; unsigned int u[4]; } nb;
                nb.s = bT;
#pragma unroll
                for (int j = 0; j < 4; ++j) nb.u[j] ^= 0x80008000u;
                bT = nb.s;
            }
            float4v a2 = float4v{0.f, 0.f, 0.f, 0.f};
            a2 = __builtin_amdgcn_mfma_f32_16x16x32_bf16(w1, aT, a2, 0, 0, 0);
            a2 = __builtin_amdgcn_mfma_f32_16x16x32_bf16(w2, bT, a2, 0, 0, 0);
            acc2[kk] = a2;
        }
        if (c < 4) {
#pragma unroll
            for (int r = 0; r < 4; ++r) {
                unsigned int u = (unsigned int)f2bf(acc2[0][r]) | ((unsigned int)f2bf(acc2[1][r]) << 16);
                *reinterpret_cast<unsigned int*>(&P[p4(c, 16 * rt + 4 * gq + r, 16 * t2 + k)]) = u;
            }
        }
    }
}

// ---------------------------------------------------------------------------
// Non-fused spectral kernel (axes M, N). 4 lines/block, ~18.5 KB LDS.
// MODE: 0 = store f32 to out, 1 = accum f32 in out,
//       2 = store bf16 to pw,  3 = accum bf16 in pw.
// ---------------------------------------------------------------------------
template <int AXIS, int MODE>
__global__ __launch_bounds__(256)
void spectral_mfma(const float* __restrict__ x,
                   const unsigned short* __restrict__ wf,
                   const unsigned short* __restrict__ tf,
                   const unsigned short* __restrict__ ti,
                   float* __restrict__ out,
                   unsigned short* __restrict__ pw)
{
    __shared__ __align__(16) unsigned short AB[AB_SHORTS];
    __shared__ __align__(16) unsigned short P[P_SHORTS];

    const int t = threadIdx.x, lane = t & 63, wave = t >> 6;
    const int gq = lane >> 4, c = lane & 15;
    constexpr int stride = (AXIS == 0) ? S_M : S_N;

    const int l = blockIdx.x * 4 + wave;
    const int b = l >> 12, p1 = (l >> 6) & 63, p2 = l & 63;
    const long bs = (AXIS == 0)
        ? (long)b * S_B + (long)p1 * S_N + (long)p2 * S_Z
        : (long)b * S_B + (long)p1 * S_M + (long)p2 * S_Z;

    stageF1<stride>(x, bs, tf, AB, lane, wave);
    __syncthreads();
    stageMx4(wf, AB, P, lane, wave);
    __syncthreads();

    short8v tiB[4];
#pragma unroll
    for (int mt = 0; mt < 4; ++mt)
        tiB[mt] = *reinterpret_cast<const short8v*>(ti + (mt * 64 + lane) * 8);

    short8v pA[2];
    pA[0] = *reinterpret_cast<const short8v*>(&P[p4(wave, c, 8 * gq)]);
    pA[1] = *reinterpret_cast<const short8v*>(&P[p4(wave, 16 + c, 8 * gq)]);

#pragma unroll
    for (int rt = 0; rt < 2; ++rt)
#pragma unroll
        for (int mt = 0; mt < 4; ++mt) {
            float4v acc = float4v{0.f, 0.f, 0.f, 0.f};
            acc = __builtin_amdgcn_mfma_f32_16x16x32_bf16(pA[rt], tiB[mt], acc, 0, 0, 0);
            const long off = bs + (long)(16 * mt + c) * stride + 16 * rt + 4 * gq;
            if (MODE == 0) {
                *reinterpret_cast<float4*>(out + off) = make_float4(acc[0], acc[1], acc[2], acc[3]);
            } else if (MODE == 1) {
                float4 old = *reinterpret_cast<const float4*>(out + off);
                old.x += acc[0]; old.y += acc[1]; old.z += acc[2]; old.w += acc[3];
                *reinterpret_cast<float4*>(out + off) = old;
            } else if (MODE == 2) {
                uint2 pv;
                pv.x = (unsigned int)f2bf(acc[0]) | ((unsigned int)f2bf(acc[1]) << 16);
                pv.y = (unsigned int)f2bf(acc[2]) | ((unsigned int)f2bf(acc[3]) << 16);
                *reinterpret_cast<uint2*>(pw + off) = pv;
            } else {
                uint2 old = *reinterpret_cast<const uint2*>(pw + off);
                const float v0 = bf2f(old.x & 0xffffu) + acc[0];
                const float v1 = bf2f(old.x >> 16)     + acc[1];
                const float v2 = bf2f(old.y & 0xffffu) + acc[2];
                const float v3 = bf2f(old.y >> 16)     + acc[3];
                uint2 pv;
                pv.x = (unsigned int)f2bf(v0) | ((unsigned int)f2bf(v1) << 16);
                pv.y = (unsigned int)f2bf(v2) | ((unsigned int)f2bf(v3) << 16);
                *reinterpret_cast<uint2*>(pw + off) = pv;
            }
        }
}

// ---------------------------------------------------------------------------
// Fused axis-Z spectral + FFN + LayerNorm. 4 lines/block, ~46 KB LDS.
// LDS regions (shorts), barrier-separated reuse:
//   [0,8192)       AB (4096 used) -> (after Mx) FFN weight fragments (8192)
//   [8192,13344)   P
//   [13344,23584)  S = sum tile [line 4][pt 64][ch pad 40] bf16; each wave's
//                  H buffer overlays its OWN line's S slab (consumed into
//                  registers before first H write -> no extra region).
// BF16P: partial is bf16 in ws (else f32 in out).
// ---------------------------------------------------------------------------
template <bool BF16P>
__global__ __launch_bounds__(256)
void spectral_fused(const float* __restrict__ x,
                    const unsigned short* __restrict__ wf,
                    const unsigned short* __restrict__ tf,
                    const unsigned short* __restrict__ ti,
                    const float* __restrict__ w0, const float* __restrict__ b0,
                    const float* __restrict__ w1, const float* __restrict__ b1,
                    const float* __restrict__ g,  const float* __restrict__ bb,
                    const void* __restrict__ partial,
                    float* __restrict__ out)
{
    __shared__ __align__(16) unsigned short sm[23584];
    constexpr int OP = 8192, OS = 13344;

    const int t = threadIdx.x, lane = t & 63, wave = t >> 6;
    const int gq = lane >> 4, c = lane & 15;

    const int l = blockIdx.x * 4 + wave;
    const int b = l >> 12, p1 = (l >> 6) & 63, p2 = l & 63;
    const long bs = (long)b * S_B + (long)p1 * S_M + (long)p2 * S_N;

    float b0v[8], b1v[2], gv[2], bvv[2];
#pragma unroll
    for (int n = 0; n < 8; ++n) b0v[n] = b0[n * 16 + c];
#pragma unroll
    for (int n = 0; n < 2; ++n) { b1v[n] = b1[n * 16 + c]; gv[n] = g[n * 16 + c]; bvv[n] = bb[n * 16 + c]; }

    stageF1<S_Z>(x, bs, tf, sm, lane, wave);
    __syncthreads();
    stageMx4(wf, sm, sm + OP, lane, wave);
    __syncthreads();

    // ---- FFN weight fragments into dead AB region ----
    for (int s = t; s < 512; s += 256) {
        const int n = s >> 6, ln = s & 63, g2 = ln >> 4, c2 = ln & 15;
        const int kb = n >> 1, nn = n & 1;
        short8v v0, v1;
#pragma unroll
        for (int e = 0; e < 8; ++e) {
            v0[e] = (short)f2bf(w0[(8 * g2 + e) * 128 + n * 16 + c2]);
            v1[e] = (short)f2bf(w1[(32 * kb + 8 * g2 + e) * 32 + nn * 16 + c2]);
        }
        *reinterpret_cast<short8v*>(&sm[s * 8])        = v0;
        *reinterpret_cast<short8v*>(&sm[4096 + s * 8]) = v1;
    }

    // ---- stage I: S = partial(xx+xy) + axis-z result, bf16 in LDS ----
    short8v tiB[4];
#pragma unroll
    for (int mt = 0; mt < 4; ++mt)
        tiB[mt] = *reinterpret_cast<const short8v*>(ti + (mt * 64 + lane) * 8);

    {
        short8v pA[2];
        pA[0] = *reinterpret_cast<const short8v*>(&sm[OP + p4(wave, c, 8 * gq)]);
        pA[1] = *reinterpret_cast<const short8v*>(&sm[OP + p4(wave, 16 + c, 8 * gq)]);
#pragma unroll
        for (int rt = 0; rt < 2; ++rt)
#pragma unroll
            for (int mt = 0; mt < 4; ++mt) {
                float4v acc = float4v{0.f, 0.f, 0.f, 0.f};
                acc = __builtin_amdgcn_mfma_f32_16x16x32_bf16(pA[rt], tiB[mt], acc, 0, 0, 0);
                const long off = bs + (long)(16 * mt + c) * S_Z + 16 * rt + 4 * gq;
                float v0, v1, v2, v3;
                if (BF16P) {
                    uint2 pv = *reinterpret_cast<const uint2*>((const unsigned short*)partial + off);
                    v0 = bf2f(pv.x & 0xffffu) + acc[0];
                    v1 = bf2f(pv.x >> 16)     + acc[1];
                    v2 = bf2f(pv.y & 0xffffu) + acc[2];
                    v3 = bf2f(pv.y >> 16)     + acc[3];
                } else {
                    float4 old = *reinterpret_cast<const float4*>((const float*)partial + off);
                    v0 = old.x + acc[0]; v1 = old.y + acc[1];
                    v2 = old.z + acc[2]; v3 = old.w + acc[3];
                }
                const int si = OS + (wave * 64 + 16 * mt + c) * 40 + 16 * rt + 4 * gq;
                *reinterpret_cast<unsigned int*>(&sm[si])     = (unsigned int)f2bf(v0) | ((unsigned int)f2bf(v1) << 16);
                *reinterpret_cast<unsigned int*>(&sm[si + 2]) = (unsigned int)f2bf(v2) | ((unsigned int)f2bf(v3) << 16);
            }
    }
    __syncthreads();

    // ---- FFN + LN, 1 tile per wave; H overlays own S slab ----
    const int Hb = OS + wave * 2560;

    short8v af[4];
#pragma unroll
    for (int f = 0; f < 4; ++f)
        af[f] = *reinterpret_cast<const short8v*>(&sm[OS + (wave * 64 + 16 * f + c) * 40 + 8 * gq]);

    float4v Y[4][2];
#pragma unroll
    for (int f = 0; f < 4; ++f)
#pragma unroll
        for (int n = 0; n < 2; ++n)
            Y[f][n] = float4v{b1v[n], b1v[n], b1v[n], b1v[n]};

#pragma unroll
    for (int kb = 0; kb < 4; ++kb) {
#pragma unroll
        for (int nn = 0; nn < 2; ++nn) {
            const int n = 2 * kb + nn;
            const short8v wv = *reinterpret_cast<const short8v*>(&sm[(n * 64 + lane) * 8]);
#pragma unroll
            for (int f = 0; f < 4; ++f) {
                float4v hacc = float4v{b0v[n], b0v[n], b0v[n], b0v[n]};
                hacc = __builtin_amdgcn_mfma_f32_16x16x32_bf16(af[f], wv, hacc, 0, 0, 0);
#pragma unroll
                for (int r = 0; r < 4; ++r)
                    sm[Hb + (16 * f + 4 * gq + r) * 40 + nn * 16 + c] = f2bf(fmaxf(hacc[r], 0.f));
            }
        }
        const short8v wva = *reinterpret_cast<const short8v*>(&sm[4096 + ((kb * 2 + 0) * 64 + lane) * 8]);
        const short8v wvb = *reinterpret_cast<const short8v*>(&sm[4096 + ((kb * 2 + 1) * 64 + lane) * 8]);
#pragma unroll
        for (int f = 0; f < 4; ++f) {
            const short8v a2 = *reinterpret_cast<const short8v*>(&sm[Hb + (16 * f + c) * 40 + 8 * gq]);
            Y[f][0] = __builtin_amdgcn_mfma_f32_16x16x32_bf16(a2, wva, Y[f][0], 0, 0, 0);
            Y[f][1] = __builtin_amdgcn_mfma_f32_16x16x32_bf16(a2, wvb, Y[f][1], 0, 0, 0);
        }
    }

#pragma unroll
    for (int f = 0; f < 4; ++f) {
        float smv[4], sq[4];
#pragma unroll
        for (int r = 0; r < 4; ++r) {
            const float v0 = Y[f][0][r], v1 = Y[f][1][r];
            smv[r] = v0 + v1;
            sq[r]  = v0 * v0 + v1 * v1;
        }
#pragma unroll
        for (int mask = 1; mask <= 8; mask <<= 1) {
#pragma unroll
            for (int r = 0; r < 4; ++r) {
                smv[r] += __shfl_xor(smv[r], mask);
                sq[r]  += __shfl_xor(sq[r], mask);
            }
        }
#pragma unroll
        for (int r = 0; r < 4; ++r) {
            const float mu = smv[r] * (1.0f / 32.0f);
            const float var = sq[r] * (1.0f / 32.0f) - mu * mu;
            const float rs = rsqrtf(var + 1e-5f);
            float* op = out + bs + (long)(16 * f + 4 * gq + r) * 32;
            op[c]      = (Y[f][0][r] - mu) * rs * gv[0] + bvv[0];
            op[16 + c] = (Y[f][1][r] - mu) * rs * gv[1] + bvv[1];
        }
    }
}

extern "C" void kernel_launch(void* const* d_in, const int* in_sizes, int n_in,
                              void* d_out, int out_size, void* d_ws, size_t ws_size,
                              hipStream_t stream)
{
    const float* x    = (const float*)d_in[0];
    const float* wx   = (const float*)d_in[1];
    const float* wy   = (const float*)d_in[2];
    const float* wz   = (const float*)d_in[3];
    const float* w0   = (const float*)d_in[4];
    const float* b0   = (const float*)d_in[5];
    const float* w1   = (const float*)d_in[6];
    const float* b1   = (const float*)d_in[7];
    const float* ln_g = (const float*)d_in[8];
    const float* ln_b = (const float*)d_in[9];
    float* out = (float*)d_out;

    unsigned short* wsf = (unsigned short*)d_ws;

    const size_t PART_OFF   = 262144;                       // frag region < 256 KB
    const size_t PART_BYTES = (size_t)33554432 * 2;         // 64 MB bf16 partial
    const bool bf16p = ws_size >= PART_OFF + PART_BYTES;
    unsigned short* pw = (unsigned short*)((char*)d_ws + PART_OFF);

    setup_frags<<<100, 256, 0, stream>>>(wx, wy, wz, wsf);

    // 16384 lines per axis / 4 per block = 4096 blocks
    if (bf16p) {
        spectral_mfma<0, 2><<<4096, 256, 0, stream>>>(x, wsf + 0 * 32768, wsf + WS_TF, wsf + WS_TI, out, pw);
        spectral_mfma<1, 3><<<4096, 256, 0, stream>>>(x, wsf + 1 * 32768, wsf + WS_TF, wsf + WS_TI, out, pw);
        spectral_fused<true><<<4096, 256, 0, stream>>>(x, wsf + 2 * 32768, wsf + WS_TF, wsf + WS_TI,
                                                       w0, b0, w1, b1, ln_g, ln_b, pw, out);
    } else {
        spectral_mfma<0, 0><<<4096, 256, 0, stream>>>(x, wsf + 0 * 32768, wsf + WS_TF, wsf + WS_TI, out, pw);
        spectral_mfma<1, 1><<<4096, 256, 0, stream>>>(x, wsf + 1 * 32768, wsf + WS_TF, wsf + WS_TI, out, pw);
        spectral_fused<false><<<4096, 256, 0, stream>>>(x, wsf + 2 * 32768, wsf + WS_TF, wsf + WS_TI,
                                                        w0, b0, w1, b1, ln_g, ln_b, out, out);
    }
}

// Round 8
// 225.943 us; speedup vs baseline: 15.4116x; 1.0140x over previous
//
#include <hip/hip_runtime.h>
#include <math.h>

typedef __attribute__((ext_vector_type(8))) short short8v;
typedef __attribute__((ext_vector_type(4))) float float4v;

constexpr float THETA = 6.28318530717958647692f / 64.0f;  // 2*pi/64

// strides in floats for layout [b][m][n][z][c], c=32
constexpr int S_B = 64 * 64 * 64 * 32;
constexpr int S_M = 64 * 64 * 32;
constexpr int S_N = 64 * 32;
constexpr int S_Z = 32;

// Native bf16 conversion (RNE) — compiler lowers pairs to v_cvt_pk_bf16_f32.
__device__ __forceinline__ unsigned short f2bf(float f) {
    __bf16 h = (__bf16)f;
    return __builtin_bit_cast(unsigned short, h);
}
__device__ __forceinline__ unsigned int pkbf(float lo, float hi) {
    return (unsigned int)f2bf(lo) | ((unsigned int)f2bf(hi) << 16);
}
__device__ __forceinline__ float bf2f(unsigned int h) {
    return __builtin_bit_cast(float, h << 16);
}

// ---------------------------------------------------------------------------
// ws fragment layout (ushort units) — unchanged:
//   Wf: [ax 3][k 16][wt 2 (0=wr,1=wi)][rt 2][lane 64][e 8]   @ 0        (98304)
//   Tf: [jt 2][s 2][lane][e]                                  @ 98304    (2048)
//   Ti: [mt 4][lane][e]                                       @ 100352   (2048)
// k-slot convention everywhere: k = 8*(lane>>4) + e (A and B share bijection).
// ---------------------------------------------------------------------------
constexpr int WS_TF = 98304, WS_TI = 100352, WS_TOTAL = 102400;

__global__ __launch_bounds__(256)
void setup_frags(const float* __restrict__ wx, const float* __restrict__ wy,
                 const float* __restrict__ wz, unsigned short* __restrict__ W)
{
    int f0 = (blockIdx.x * 256 + threadIdx.x) * 4;
#pragma unroll
    for (int u = 0; u < 4; ++u) {
        int f = f0 + u;
        if (f >= WS_TOTAL) continue;
        unsigned short v;
        if (f < WS_TF) {
            int ax = f >> 15, rem = f & 32767;
            int k = rem >> 11;
            int rem2 = rem & 2047;
            int wt = rem2 >> 10, rt = (rem2 >> 9) & 1, l = (rem2 >> 3) & 63, e = rem2 & 7;
            int o = 16 * rt + (l & 15), i = 8 * (l >> 4) + e;
            const float* w = (ax == 0) ? wx : ((ax == 1) ? wy : wz);
            v = f2bf(w[((i * 32 + o) * 16 + k) * 2 + wt]);
        } else if (f < WS_TI) {
            int rem = f - WS_TF;
            int jt = rem >> 10, s = (rem >> 9) & 1, l = (rem >> 3) & 63, e = rem & 7;
            int kk = l & 15, m = 32 * s + 8 * (l >> 4) + e;
            int jm = (kk * m) & 63;
            float ang = THETA * (float)jm;
            v = f2bf(jt == 0 ? cosf(ang) : sinf(ang));
        } else {
            int rem = f - WS_TI;
            int mt = rem >> 9, l = (rem >> 3) & 63, e = rem & 7;
            int mp = 16 * mt + (l & 15), r = 8 * (l >> 4) + e;
            int k = r & 15;
            float sk = (k == 0) ? (1.0f / 64.0f) : (2.0f / 64.0f);
            int jm = (k * mp) & 63;
            float ang = THETA * (float)jm;
            v = f2bf(r < 16 ? sk * cosf(ang) : -sk * sinf(ang));
        }
        W[f] = v;
    }
}

// AB: [t 2][k 16][line 4][i 32] bf16, 64-B rows, XOR swizzle (bijective).
constexpr int AB_SHORTS = 4096;   // 8 KB
__device__ __forceinline__ int ab4(int t, int k, int line, int i) {
    return ((((t * 16 + k) * 4 + line) * 64) + i * 2) ^ (((line ^ k) & 7) << 4);
}
// P: [line 4][o 32][r 40] ushort, line stride 1288 (strides not 0 mod 128 B).
constexpr int P_LS = 1288;
constexpr int P_SHORTS = 4 * P_LS;  // 5152
__device__ __forceinline__ int p4(int line, int o, int r) {
    return line * P_LS + o * 40 + r;
}

// ---- stage F: forward transform, 1 line per wave, A = x direct from global ----
template <int STRIDE>
__device__ __forceinline__ void stageF1(const float* __restrict__ x, long bs,
                                        const unsigned short* __restrict__ tf,
                                        unsigned short* __restrict__ AB,
                                        int lane, int line)
{
    const int gq = lane >> 4, c = lane & 15;
    short8v tfB[2][2];
#pragma unroll
    for (int jt = 0; jt < 2; ++jt)
#pragma unroll
        for (int s = 0; s < 2; ++s)
            tfB[jt][s] = *reinterpret_cast<const short8v*>(tf + ((jt * 2 + s) * 64 + lane) * 8);

    float4v acc[2][2];
#pragma unroll
    for (int rt = 0; rt < 2; ++rt)
#pragma unroll
        for (int jt = 0; jt < 2; ++jt)
            acc[rt][jt] = float4v{0.f, 0.f, 0.f, 0.f};

#pragma unroll
    for (int rt = 0; rt < 2; ++rt) {
        const float* xp = x + bs + 16 * rt + c;
#pragma unroll
        for (int s = 0; s < 2; ++s) {
            short8v a;
#pragma unroll
            for (int e = 0; e < 8; ++e)
                a[e] = (short)f2bf(xp[(long)(32 * s + 8 * gq + e) * STRIDE]);
            acc[rt][0] = __builtin_amdgcn_mfma_f32_16x16x32_bf16(a, tfB[0][s], acc[rt][0], 0, 0, 0);
            acc[rt][1] = __builtin_amdgcn_mfma_f32_16x16x32_bf16(a, tfB[1][s], acc[rt][1], 0, 0, 0);
        }
    }
#pragma unroll
    for (int rt = 0; rt < 2; ++rt)
#pragma unroll
        for (int jt = 0; jt < 2; ++jt) {
            *reinterpret_cast<uint2*>(reinterpret_cast<char*>(AB) + ab4(jt, c, line, 16 * rt + 4 * gq)) =
                make_uint2(pkbf(acc[rt][jt][0], acc[rt][jt][1]), pkbf(acc[rt][jt][2], acc[rt][jt][3]));
        }
}

// ---- stage Mx: complex channel mixing; wave owns (Pr/Pi, o-half) quadrant ----
__device__ __forceinline__ void stageMx4(const unsigned short* __restrict__ wf,
                                         const unsigned short* __restrict__ AB,
                                         unsigned short* __restrict__ P,
                                         int lane, int wave)
{
    const int gq = lane >> 4, c = lane & 15;
    const int t2 = wave >> 1, rt = wave & 1, lc = c & 3;
    for (int k = 0; k < 16; k += 2) {
        float4v acc2[2];
#pragma unroll
        for (int kk = 0; kk < 2; ++kk) {
            const int kc = k + kk;
            short8v aT = *reinterpret_cast<const short8v*>(reinterpret_cast<const char*>(AB) + ab4(0, kc, lc, 8 * gq));
            short8v bT = *reinterpret_cast<const short8v*>(reinterpret_cast<const char*>(AB) + ab4(1, kc, lc, 8 * gq));
            const int w1t = t2 ? 1 : 0, w2t = t2 ? 0 : 1;
            short8v w1 = *reinterpret_cast<const short8v*>(wf + (((kc * 2 + w1t) * 2 + rt) * 64 + lane) * 8);
            short8v w2 = *reinterpret_cast<const short8v*>(wf + (((kc * 2 + w2t) * 2 + rt) * 64 + lane) * 8);
            if (t2) {
                union { short8v s; unsigned int u[4]; } nb;
                nb.s = bT;
#pragma unroll
                for (int j = 0; j < 4; ++j) nb.u[j] ^= 0x80008000u;
                bT = nb.s;
            }
            float4v a2 = float4v{0.f, 0.f, 0.f, 0.f};
            a2 = __builtin_amdgcn_mfma_f32_16x16x32_bf16(w1, aT, a2, 0, 0, 0);
            a2 = __builtin_amdgcn_mfma_f32_16x16x32_bf16(w2, bT, a2, 0, 0, 0);
            acc2[kk] = a2;
        }
        if (c < 4) {
#pragma unroll
            for (int r = 0; r < 4; ++r) {
                *reinterpret_cast<unsigned int*>(&P[p4(c, 16 * rt + 4 * gq + r, 16 * t2 + k)]) =
                    pkbf(acc2[0][r], acc2[1][r]);
            }
        }
    }
}

// ---- spectral line body (stages F, Mx, I) writing bf16 partial ----
template <int AXIS>
__device__ __forceinline__ void spectral_body(const float* __restrict__ x,
                                              const unsigned short* __restrict__ wf,
                                              const unsigned short* __restrict__ tf,
                                              const unsigned short* __restrict__ ti,
                                              unsigned short* __restrict__ pw,
                                              unsigned short* __restrict__ AB,
                                              unsigned short* __restrict__ P,
                                              int l, int lane, int wave)
{
    constexpr int stride = (AXIS == 0) ? S_M : S_N;
    const int b = l >> 12, p1 = (l >> 6) & 63, p2 = l & 63;
    const long bs = (AXIS == 0)
        ? (long)b * S_B + (long)p1 * S_N + (long)p2 * S_Z
        : (long)b * S_B + (long)p1 * S_M + (long)p2 * S_Z;
    const int gq = lane >> 4, c = lane & 15;

    stageF1<stride>(x, bs, tf, AB, lane, wave);
    __syncthreads();
    stageMx4(wf, AB, P, lane, wave);
    __syncthreads();

    short8v tiB[4];
#pragma unroll
    for (int mt = 0; mt < 4; ++mt)
        tiB[mt] = *reinterpret_cast<const short8v*>(ti + (mt * 64 + lane) * 8);

    short8v pA[2];
    pA[0] = *reinterpret_cast<const short8v*>(&P[p4(wave, c, 8 * gq)]);
    pA[1] = *reinterpret_cast<const short8v*>(&P[p4(wave, 16 + c, 8 * gq)]);

#pragma unroll
    for (int rt = 0; rt < 2; ++rt)
#pragma unroll
        for (int mt = 0; mt < 4; ++mt) {
            float4v acc = float4v{0.f, 0.f, 0.f, 0.f};
            acc = __builtin_amdgcn_mfma_f32_16x16x32_bf16(pA[rt], tiB[mt], acc, 0, 0, 0);
            const long off = bs + (long)(16 * mt + c) * stride + 16 * rt + 4 * gq;
            *reinterpret_cast<uint2*>(pw + off) =
                make_uint2(pkbf(acc[0], acc[1]), pkbf(acc[2], acc[3]));
        }
}

// ---------------------------------------------------------------------------
// Merged axes M+N kernel (tier2): blocks [0,4096) axis0 -> pw1,
// [4096,8192) axis1 -> pw2. No RMW, no cross-block ordering dependence.
// ---------------------------------------------------------------------------
__global__ __launch_bounds__(256)
void spectral_xy(const float* __restrict__ x,
                 const unsigned short* __restrict__ wf0,
                 const unsigned short* __restrict__ wf1,
                 const unsigned short* __restrict__ tf,
                 const unsigned short* __restrict__ ti,
                 unsigned short* __restrict__ pw1,
                 unsigned short* __restrict__ pw2)
{
    __shared__ __align__(16) unsigned short AB[AB_SHORTS];
    __shared__ __align__(16) unsigned short P[P_SHORTS];
    const int t = threadIdx.x, lane = t & 63, wave = t >> 6;
    if (blockIdx.x < 4096) {
        spectral_body<0>(x, wf0, tf, ti, pw1, AB, P, blockIdx.x * 4 + wave, lane, wave);
    } else {
        spectral_body<1>(x, wf1, tf, ti, pw2, AB, P, (blockIdx.x - 4096) * 4 + wave, lane, wave);
    }
}

// ---------------------------------------------------------------------------
// Non-fused spectral kernel (tier1/tier0 fallback).
// MODE: 0 = store f32 to out, 1 = accum f32 in out,
//       2 = store bf16 to pw,  3 = accum bf16 in pw.
// ---------------------------------------------------------------------------
template <int AXIS, int MODE>
__global__ __launch_bounds__(256)
void spectral_mfma(const float* __restrict__ x,
                   const unsigned short* __restrict__ wf,
                   const unsigned short* __restrict__ tf,
                   const unsigned short* __restrict__ ti,
                   float* __restrict__ out,
                   unsigned short* __restrict__ pw)
{
    __shared__ __align__(16) unsigned short AB[AB_SHORTS];
    __shared__ __align__(16) unsigned short P[P_SHORTS];

    const int t = threadIdx.x, lane = t & 63, wave = t >> 6;
    const int gq = lane >> 4, c = lane & 15;
    constexpr int stride = (AXIS == 0) ? S_M : S_N;

    const int l = blockIdx.x * 4 + wave;
    const int b = l >> 12, p1 = (l >> 6) & 63, p2 = l & 63;
    const long bs = (AXIS == 0)
        ? (long)b * S_B + (long)p1 * S_N + (long)p2 * S_Z
        : (long)b * S_B + (long)p1 * S_M + (long)p2 * S_Z;

    stageF1<stride>(x, bs, tf, AB, lane, wave);
    __syncthreads();
    stageMx4(wf, AB, P, lane, wave);
    __syncthreads();

    short8v tiB[4];
#pragma unroll
    for (int mt = 0; mt < 4; ++mt)
        tiB[mt] = *reinterpret_cast<const short8v*>(ti + (mt * 64 + lane) * 8);

    short8v pA[2];
    pA[0] = *reinterpret_cast<const short8v*>(&P[p4(wave, c, 8 * gq)]);
    pA[1] = *reinterpret_cast<const short8v*>(&P[p4(wave, 16 + c, 8 * gq)]);

#pragma unroll
    for (int rt = 0; rt < 2; ++rt)
#pragma unroll
        for (int mt = 0; mt < 4; ++mt) {
            float4v acc = float4v{0.f, 0.f, 0.f, 0.f};
            acc = __builtin_amdgcn_mfma_f32_16x16x32_bf16(pA[rt], tiB[mt], acc, 0, 0, 0);
            const long off = bs + (long)(16 * mt + c) * stride + 16 * rt + 4 * gq;
            if (MODE == 0) {
                *reinterpret_cast<float4*>(out + off) = make_float4(acc[0], acc[1], acc[2], acc[3]);
            } else if (MODE == 1) {
                float4 old = *reinterpret_cast<const float4*>(out + off);
                old.x += acc[0]; old.y += acc[1]; old.z += acc[2]; old.w += acc[3];
                *reinterpret_cast<float4*>(out + off) = old;
            } else if (MODE == 2) {
                *reinterpret_cast<uint2*>(pw + off) =
                    make_uint2(pkbf(acc[0], acc[1]), pkbf(acc[2], acc[3]));
            } else {
                uint2 old = *reinterpret_cast<const uint2*>(pw + off);
                const float v0 = bf2f(old.x & 0xffffu) + acc[0];
                const float v1 = bf2f(old.x >> 16)     + acc[1];
                const float v2 = bf2f(old.y & 0xffffu) + acc[2];
                const float v3 = bf2f(old.y >> 16)     + acc[3];
                *reinterpret_cast<uint2*>(pw + off) =
                    make_uint2(pkbf(v0, v1), pkbf(v2, v3));
            }
        }
}

// ---------------------------------------------------------------------------
// Fused axis-Z spectral + FFN + LayerNorm. 4 lines/block, ~46 KB LDS.
// NPART: 0 = f32 partial in out; 1 = one bf16 partial; 2 = two bf16 partials.
// FFN GEMM1 is operand-swapped (A = W0^T frags, B = S^T) so D rows = hidden:
// the 4 per-lane H values are contiguous in [point][hidden pad 40] -> b64
// writes (same staged weight bytes as before; only the operand order flips).
// ---------------------------------------------------------------------------
template <int NPART>
__global__ __launch_bounds__(256)
void spectral_fused(const float* __restrict__ x,
                    const unsigned short* __restrict__ wf,
                    const unsigned short* __restrict__ tf,
                    const unsigned short* __restrict__ ti,
                    const float* __restrict__ w0, const float* __restrict__ b0,
                    const float* __restrict__ w1, const float* __restrict__ b1,
                    const float* __restrict__ g,  const float* __restrict__ bb,
                    const unsigned short* __restrict__ pw1,
                    const unsigned short* __restrict__ pw2,
                    const float* __restrict__ pf32,
                    float* __restrict__ out)
{
    __shared__ __align__(16) unsigned short sm[23584];
    constexpr int OP = 8192, OS = 13344;

    const int t = threadIdx.x, lane = t & 63, wave = t >> 6;
    const int gq = lane >> 4, c = lane & 15;

    const int l = blockIdx.x * 4 + wave;
    const int b = l >> 12, p1 = (l >> 6) & 63, p2 = l & 63;
    const long bs = (long)b * S_B + (long)p1 * S_M + (long)p2 * S_N;

    // hoisted per-lane constants: GEMM1 bias is row-indexed (b0[16n+4gq+r]),
    // GEMM2 bias / LN params are col-indexed.
    float4 b0q[8];
#pragma unroll
    for (int n = 0; n < 8; ++n)
        b0q[n] = *reinterpret_cast<const float4*>(b0 + 16 * n + 4 * gq);
    float b1v[2], gv[2], bvv[2];
#pragma unroll
    for (int n = 0; n < 2; ++n) { b1v[n] = b1[n * 16 + c]; gv[n] = g[n * 16 + c]; bvv[n] = bb[n * 16 + c]; }

    stageF1<S_Z>(x, bs, tf, sm, lane, wave);
    __syncthreads();
    stageMx4(wf, sm, sm + OP, lane, wave);
    __syncthreads();

    // ---- FFN weight fragments into dead AB region (bytes identical to the
    //      unswapped version; fragment data is operand-role agnostic) ----
    for (int s = t; s < 512; s += 256) {
        const int n = s >> 6, ln = s & 63, g2 = ln >> 4, c2 = ln & 15;
        const int kb = n >> 1, nn = n & 1;
        short8v v0, v1;
#pragma unroll
        for (int e = 0; e < 8; ++e) {
            v0[e] = (short)f2bf(w0[(8 * g2 + e) * 128 + n * 16 + c2]);
            v1[e] = (short)f2bf(w1[(32 * kb + 8 * g2 + e) * 32 + nn * 16 + c2]);
        }
        *reinterpret_cast<short8v*>(&sm[s * 8])        = v0;
        *reinterpret_cast<short8v*>(&sm[4096 + s * 8]) = v1;
    }

    // ---- stage I: S = partial(xx+xy) + axis-z result, bf16 in LDS ----
    short8v tiB[4];
#pragma unroll
    for (int mt = 0; mt < 4; ++mt)
        tiB[mt] = *reinterpret_cast<const short8v*>(ti + (mt * 64 + lane) * 8);

    {
        short8v pA[2];
        pA[0] = *reinterpret_cast<const short8v*>(&sm[OP + p4(wave, c, 8 * gq)]);
        pA[1] = *reinterpret_cast<const short8v*>(&sm[OP + p4(wave, 16 + c, 8 * gq)]);
#pragma unroll
        for (int rt = 0; rt < 2; ++rt)
#pragma unroll
            for (int mt = 0; mt < 4; ++mt) {
                float4v acc = float4v{0.f, 0.f, 0.f, 0.f};
                acc = __builtin_amdgcn_mfma_f32_16x16x32_bf16(pA[rt], tiB[mt], acc, 0, 0, 0);
                const long off = bs + (long)(16 * mt + c) * S_Z + 16 * rt + 4 * gq;
                float v0, v1, v2, v3;
                if (NPART == 0) {
                    float4 old = *reinterpret_cast<const float4*>(pf32 + off);
                    v0 = old.x + acc[0]; v1 = old.y + acc[1];
                    v2 = old.z + acc[2]; v3 = old.w + acc[3];
                } else {
                    uint2 pv = *reinterpret_cast<const uint2*>(pw1 + off);
                    v0 = bf2f(pv.x & 0xffffu) + acc[0];
                    v1 = bf2f(pv.x >> 16)     + acc[1];
                    v2 = bf2f(pv.y & 0xffffu) + acc[2];
                    v3 = bf2f(pv.y >> 16)     + acc[3];
                    if (NPART == 2) {
                        uint2 qv = *reinterpret_cast<const uint2*>(pw2 + off);
                        v0 += bf2f(qv.x & 0xffffu);
                        v1 += bf2f(qv.x >> 16);
                        v2 += bf2f(qv.y & 0xffffu);
                        v3 += bf2f(qv.y >> 16);
                    }
                }
                const int si = OS + (wave * 64 + 16 * mt + c) * 40 + 16 * rt + 4 * gq;
                *reinterpret_cast<uint2*>(&sm[si]) = make_uint2(pkbf(v0, v1), pkbf(v2, v3));
            }
    }
    __syncthreads();

    // ---- FFN + LN, 1 tile per wave; H overlays own S slab ----
    const int Hb = OS + wave * 2560;

    short8v af[4];
#pragma unroll
    for (int f = 0; f < 4; ++f)
        af[f] = *reinterpret_cast<const short8v*>(&sm[OS + (wave * 64 + 16 * f + c) * 40 + 8 * gq]);

    float4v Y[4][2];
#pragma unroll
    for (int f = 0; f < 4; ++f)
#pragma unroll
        for (int n = 0; n < 2; ++n)
            Y[f][n] = float4v{b1v[n], b1v[n], b1v[n], b1v[n]};

#pragma unroll
    for (int kb = 0; kb < 4; ++kb) {
        // GEMM1 (swapped): D^T rows = hidden j = 16nn+4gq+r, col = point 16f+c
#pragma unroll
        for (int nn = 0; nn < 2; ++nn) {
            const int n = 2 * kb + nn;
            const short8v wv = *reinterpret_cast<const short8v*>(&sm[(n * 64 + lane) * 8]);
#pragma unroll
            for (int f = 0; f < 4; ++f) {
                float4v hacc = float4v{b0q[n].x, b0q[n].y, b0q[n].z, b0q[n].w};
                hacc = __builtin_amdgcn_mfma_f32_16x16x32_bf16(wv, af[f], hacc, 0, 0, 0);
                const float h0 = fmaxf(hacc[0], 0.f), h1 = fmaxf(hacc[1], 0.f);
                const float h2 = fmaxf(hacc[2], 0.f), h3 = fmaxf(hacc[3], 0.f);
                *reinterpret_cast<uint2*>(&sm[Hb + (16 * f + c) * 40 + 16 * nn + 4 * gq]) =
                    make_uint2(pkbf(h0, h1), pkbf(h2, h3));
            }
        }
        const short8v wva = *reinterpret_cast<const short8v*>(&sm[4096 + ((kb * 2 + 0) * 64 + lane) * 8]);
        const short8v wvb = *reinterpret_cast<const short8v*>(&sm[4096 + ((kb * 2 + 1) * 64 + lane) * 8]);
#pragma unroll
        for (int f = 0; f < 4; ++f) {
            const short8v a2 = *reinterpret_cast<const short8v*>(&sm[Hb + (16 * f + c) * 40 + 8 * gq]);
            Y[f][0] = __builtin_amdgcn_mfma_f32_16x16x32_bf16(a2, wva, Y[f][0], 0, 0, 0);
            Y[f][1] = __builtin_amdgcn_mfma_f32_16x16x32_bf16(a2, wvb, Y[f][1], 0, 0, 0);
        }
    }

#pragma unroll
    for (int f = 0; f < 4; ++f) {
        float smv[4], sq[4];
#pragma unroll
        for (int r = 0; r < 4; ++r) {
            const float v0 = Y[f][0][r], v1 = Y[f][1][r];
            smv[r] = v0 + v1;
            sq[r]  = v0 * v0 + v1 * v1;
        }
#pragma unroll
        for (int mask = 1; mask <= 8; mask <<= 1) {
#pragma unroll
            for (int r = 0; r < 4; ++r) {
                smv[r] += __shfl_xor(smv[r], mask);
                sq[r]  += __shfl_xor(sq[r], mask);
            }
        }
#pragma unroll
        for (int r = 0; r < 4; ++r) {
            const float mu = smv[r] * (1.0f / 32.0f);
            const float var = sq[r] * (1.0f / 32.0f) - mu * mu;
            const float rs = rsqrtf(var + 1e-5f);
            float* op = out + bs + (long)(16 * f + 4 * gq + r) * 32;
            op[c]      = (Y[f][0][r] - mu) * rs * gv[0] + bvv[0];
            op[16 + c] = (Y[f][1][r] - mu) * rs * gv[1] + bvv[1];
        }
    }
}

extern "C" void kernel_launch(void* const* d_in, const int* in_sizes, int n_in,
                              void* d_out, int out_size, void* d_ws, size_t ws_size,
                              hipStream_t stream)
{
    const float* x    = (const float*)d_in[0];
    const float* wx   = (const float*)d_in[1];
    const float* wy   = (const float*)d_in[2];
    const float* wz   = (const float*)d_in[3];
    const float* w0   = (const float*)d_in[4];
    const float* b0   = (const float*)d_in[5];
    const float* w1   = (const float*)d_in[6];
    const float* b1   = (const float*)d_in[7];
    const float* ln_g = (const float*)d_in[8];
    const float* ln_b = (const float*)d_in[9];
    float* out = (float*)d_out;

    unsigned short* wsf = (unsigned short*)d_ws;

    const size_t PART_OFF   = 262144;                 // frag region < 256 KB
    const size_t PART_BYTES = (size_t)33554432 * 2;   // 64 MB bf16 partial
    unsigned short* pw1 = (unsigned short*)((char*)d_ws + PART_OFF);
    unsigned short* pw2 = (unsigned short*)((char*)d_ws + PART_OFF + PART_BYTES);
    const int tier = (ws_size >= PART_OFF + 2 * PART_BYTES) ? 2
                   : (ws_size >= PART_OFF + PART_BYTES)     ? 1 : 0;

    setup_frags<<<100, 256, 0, stream>>>(wx, wy, wz, wsf);

    if (tier == 2) {
        spectral_xy<<<8192, 256, 0, stream>>>(x, wsf + 0 * 32768, wsf + 1 * 32768,
                                              wsf + WS_TF, wsf + WS_TI, pw1, pw2);
        spectral_fused<2><<<4096, 256, 0, stream>>>(x, wsf + 2 * 32768, wsf + WS_TF, wsf + WS_TI,
                                                    w0, b0, w1, b1, ln_g, ln_b, pw1, pw2, out, out);
    } else if (tier == 1) {
        spectral_mfma<0, 2><<<4096, 256, 0, stream>>>(x, wsf + 0 * 32768, wsf + WS_TF, wsf + WS_TI, out, pw1);
        spectral_mfma<1, 3><<<4096, 256, 0, stream>>>(x, wsf + 1 * 32768, wsf + WS_TF, wsf + WS_TI, out, pw1);
        spectral_fused<1><<<4096, 256, 0, stream>>>(x, wsf + 2 * 32768, wsf + WS_TF, wsf + WS_TI,
                                                    w0, b0, w1, b1, ln_g, ln_b, pw1, pw1, out, out);
    } else {
        spectral_mfma<0, 0><<<4096, 256, 0, stream>>>(x, wsf + 0 * 32768, wsf + WS_TF, wsf + WS_TI, out, pw1);
        spectral_mfma<1, 1><<<4096, 256, 0, stream>>>(x, wsf + 1 * 32768, wsf + WS_TF, wsf + WS_TI, out, pw1);
        spectral_fused<0><<<4096, 256, 0, stream>>>(x, wsf + 2 * 32768, wsf + WS_TF, wsf + WS_TI,
                                                    w0, b0, w1, b1, ln_g, ln_b, pw1, pw1, out, out);
    }
}